// Round 1
// baseline (2398.525 us; speedup 1.0000x reference)
//
#include <hip/hip_runtime.h>
#include <cstdint>
#include <cstddef>

#define BB 2
#define SS 2048
#define HH 1024
#define NHEADS 16
#define NKVH 4
#define HDIM 64
#define NEXP 8
#define IDIM 2048
#define NTOK (BB*SS)

typedef __bf16 bf16_t;
typedef bf16_t bf16x8 __attribute__((ext_vector_type(8)));
typedef float f32x4 __attribute__((ext_vector_type(4)));

static __device__ __forceinline__ bf16x8 cvt_bf16x8(float4 a, float4 b) {
  bf16x8 r = { (bf16_t)a.x, (bf16_t)a.y, (bf16_t)a.z, (bf16_t)a.w,
               (bf16_t)b.x, (bf16_t)b.y, (bf16_t)b.z, (bf16_t)b.w };
  return r;
}

// ---------------- RMSNorm: one block per token ----------------
__global__ __launch_bounds__(256) void rmsnorm_kernel(
    const float* __restrict__ x, const float* __restrict__ w, float* __restrict__ out)
{
  int t = blockIdx.x;
  int tid = threadIdx.x;
  float4 v = ((const float4*)(x + (size_t)t * HH))[tid];
  float ss = v.x*v.x + v.y*v.y + v.z*v.z + v.w*v.w;
  #pragma unroll
  for (int off = 32; off > 0; off >>= 1) ss += __shfl_xor(ss, off);
  __shared__ float red[4];
  if ((tid & 63) == 0) red[tid >> 6] = ss;
  __syncthreads();
  float tot = red[0] + red[1] + red[2] + red[3];
  float scale = 1.0f / sqrtf(tot / (float)HH + 1e-6f);
  float4 wv = ((const float4*)w)[tid];
  float4 o;
  o.x = v.x * scale * wv.x;
  o.y = v.y * scale * wv.y;
  o.z = v.z * scale * wv.z;
  o.w = v.w * scale * wv.w;
  ((float4*)(out + (size_t)t * HH))[tid] = o;
}

// ---------------- generic bf16-MFMA GEMM: C[M,N] = A[M,K]@W[K,N] (+R) ----------------
// 64x64 tile, BK=32, 256 threads (4 waves), wave w owns rows w*16..w*16+15.
__global__ __launch_bounds__(256) void gemm_kernel(
    const float* __restrict__ A, const float* __restrict__ W,
    const float* __restrict__ R, float* __restrict__ C,
    int N, int K)
{
  __shared__ bf16_t As[64][40];   // pad 32->40: frag b128 reads 2-way (free)
  __shared__ bf16_t Bs[64][40];   // W tile transposed: Bs[n][k]
  int tid = threadIdx.x;
  int lane = tid & 63, wid = tid >> 6;
  int m0 = blockIdx.y * 64, n0 = blockIdx.x * 64;
  const f32x4 fz = {0.f, 0.f, 0.f, 0.f};
  f32x4 acc[4]; acc[0]=fz; acc[1]=fz; acc[2]=fz; acc[3]=fz;
  int arow = tid >> 2, ac0 = (tid & 3) * 8;
  int wkk = tid >> 3, wn = (tid & 7) * 8;
  for (int k0 = 0; k0 < K; k0 += 32) {
    const float4* ap = (const float4*)(A + (size_t)(m0 + arow) * K + (k0 + ac0));
    float4 a0 = ap[0], a1 = ap[1];
    const float4* wp = (const float4*)(W + (size_t)(k0 + wkk) * N + (n0 + wn));
    float4 b0 = wp[0], b1 = wp[1];
    *(bf16x8*)(&As[arow][ac0]) = cvt_bf16x8(a0, a1);
    float tmp[8] = {b0.x,b0.y,b0.z,b0.w,b1.x,b1.y,b1.z,b1.w};
    #pragma unroll
    for (int i = 0; i < 8; ++i) Bs[wn + i][wkk] = (bf16_t)tmp[i];
    __syncthreads();
    bf16x8 af = *(const bf16x8*)(&As[wid*16 + (lane & 15)][(lane >> 4) * 8]);
    #pragma unroll
    for (int c = 0; c < 4; ++c) {
      bf16x8 bf = *(const bf16x8*)(&Bs[c*16 + (lane & 15)][(lane >> 4) * 8]);
      acc[c] = __builtin_amdgcn_mfma_f32_16x16x32_bf16(af, bf, acc[c], 0, 0, 0);
    }
    __syncthreads();
  }
  int rb = wid * 16 + (lane >> 4) * 4;
  int cb = lane & 15;
  #pragma unroll
  for (int c = 0; c < 4; ++c) {
    #pragma unroll
    for (int r = 0; r < 4; ++r) {
      size_t off = (size_t)(m0 + rb + r) * N + (n0 + c*16 + cb);
      float vv = acc[c][r];
      C[off] = R ? vv + R[off] : vv;
    }
  }
}

// ---------------- RoPE (in-place on q and k) ----------------
__global__ __launch_bounds__(256) void rope_kernel(
    float* __restrict__ q, float* __restrict__ k, const int* __restrict__ pos_ids)
{
  int idx = blockIdx.x * 256 + threadIdx.x;   // NTOK * 20 heads * 32 pairs
  int token = idx / 640;
  int rem = idx - token * 640;
  int head = rem >> 5;
  int i = rem & 31;
  float pos = (float)pos_ids[token];
  float inv = __expf(-(float)i * (9.210340371976184f / 32.0f)); // 10000^(-i/32)
  float ang = pos * inv;
  float s, c;
  sincosf(ang, &s, &c);
  float* p;
  if (head < NHEADS) p = q + (size_t)token * (NHEADS*HDIM) + head * HDIM;
  else               p = k + (size_t)token * (NKVH*HDIM) + (head - NHEADS) * HDIM;
  float x1 = p[i], x2 = p[i + 32];
  p[i]      = x1 * c - x2 * s;
  p[i + 32] = x2 * c + x1 * s;
}

// ---------------- causal GQA flash attention (fp32) ----------------
// block = 256 (4 waves), 16 q-rows per block (4 per wave), K/V chunks of 64 staged in LDS.
__global__ __launch_bounds__(256) void attn_kernel(
    const float* __restrict__ q, const float* __restrict__ k, const float* __restrict__ v,
    const int* __restrict__ amask, float* __restrict__ out)
{
  __shared__ float qs[16][64];
  __shared__ float ks[64][65];
  __shared__ float vs[64][65];
  __shared__ float ps[4][64];
  int tid = threadIdx.x, lane = tid & 63, w = tid >> 6;
  int bh = blockIdx.y;
  int b = bh >> 4, h = bh & 15, kvh = h >> 2;
  int r0 = blockIdx.x * 16;
  for (int i = tid; i < 16*64; i += 256) {
    int rr = i >> 6, d = i & 63;
    qs[rr][d] = q[((size_t)(b*SS + r0 + rr) * NHEADS + h) * HDIM + d];
  }
  float mA[4], lA[4], oA[4];
  #pragma unroll
  for (int rr = 0; rr < 4; ++rr) { mA[rr] = -1e30f; lA[rr] = 0.f; oA[rr] = 0.f; }
  int nch = r0 / 64 + 1;
  for (int c = 0; c < nch; ++c) {
    int kc = c * 64;
    __syncthreads();
    for (int i = tid; i < 64*64; i += 256) {
      int kr = i >> 6, d = i & 63;
      size_t kvoff = ((size_t)(b*SS + kc + kr) * NKVH + kvh) * HDIM + d;
      ks[kr][d] = k[kvoff];
      vs[kr][d] = v[kvoff];
    }
    __syncthreads();
    int key = kc + lane;
    bool kok = amask[b*SS + key] > 0;
    #pragma unroll 1
    for (int rr = 0; rr < 4; ++rr) {
      int row = r0 + w*4 + rr;
      float s = 0.f;
      #pragma unroll
      for (int d = 0; d < 64; ++d) s += qs[w*4+rr][d] * ks[lane][d];
      s *= 0.125f;
      bool valid = (key <= row) && kok;
      s = valid ? s : -1e30f;
      float mc = s;
      #pragma unroll
      for (int off = 32; off > 0; off >>= 1) mc = fmaxf(mc, __shfl_xor(mc, off));
      float mn = fmaxf(mA[rr], mc);
      float alpha = __expf(mA[rr] - mn);
      float p = valid ? __expf(s - mn) : 0.f;
      float psum = p;
      #pragma unroll
      for (int off = 32; off > 0; off >>= 1) psum += __shfl_xor(psum, off);
      ps[w][lane] = p;
      float o = oA[rr] * alpha;
      #pragma unroll
      for (int j = 0; j < 64; ++j) o += ps[w][j] * vs[j][lane];
      oA[rr] = o;
      lA[rr] = lA[rr] * alpha + psum;
      mA[rr] = mn;
    }
  }
  #pragma unroll
  for (int rr = 0; rr < 4; ++rr) {
    int row = r0 + w*4 + rr;
    float denom = lA[rr] > 0.f ? lA[rr] : 1.f;
    out[((size_t)(b*SS + row) * NHEADS + h) * HDIM + lane] = oA[rr] / denom;
  }
}

// ---------------- router: logits, top-2, softmax weights, expert counts ----------------
__global__ __launch_bounds__(256) void router_kernel(
    const float* __restrict__ h2, const float* __restrict__ gw,
    float* __restrict__ logits_out, int* __restrict__ sel, float* __restrict__ wts,
    int* __restrict__ counts)
{
  int tid = threadIdx.x, lane = tid & 63, w = tid >> 6;
  int tok = blockIdx.x * 4 + w;
  float acc[NEXP] = {0.f,0.f,0.f,0.f,0.f,0.f,0.f,0.f};
  const float* xr = h2 + (size_t)tok * HH;
  for (int hh = lane; hh < HH; hh += 64) {
    float xv = xr[hh];
    const float* gr = gw + (size_t)hh * NEXP;
    #pragma unroll
    for (int e = 0; e < NEXP; ++e) acc[e] += xv * gr[e];
  }
  #pragma unroll
  for (int e = 0; e < NEXP; ++e) {
    #pragma unroll
    for (int off = 32; off > 0; off >>= 1) acc[e] += __shfl_xor(acc[e], off);
  }
  if (lane == 0) {
    float* lo = logits_out + (size_t)tok * NEXP;
    #pragma unroll
    for (int e = 0; e < NEXP; ++e) lo[e] = acc[e];
    int b0 = 0; float v0 = acc[0];
    #pragma unroll
    for (int e = 1; e < NEXP; ++e) if (acc[e] > v0) { v0 = acc[e]; b0 = e; }
    int b1 = -1; float v1 = -1e38f;
    #pragma unroll
    for (int e = 0; e < NEXP; ++e) if (e != b0 && acc[e] > v1) { v1 = acc[e]; b1 = e; }
    float wa = 1.f / (1.f + __expf(v1 - v0));
    sel[tok*2] = b0; sel[tok*2+1] = b1;
    wts[tok*2] = wa; wts[tok*2+1] = 1.f - wa;
    atomicAdd(&counts[b0], 1);
    atomicAdd(&counts[b1], 1);
  }
}

__global__ void scan_kernel(const int* __restrict__ counts, int* __restrict__ offsets,
                            int* __restrict__ fill)
{
  if (threadIdx.x == 0 && blockIdx.x == 0) {
    int o = 0;
    for (int e = 0; e < NEXP; ++e) { offsets[e] = o; o += counts[e]; fill[e] = 0; }
  }
}

__global__ __launch_bounds__(256) void scatter_kernel(
    const int* __restrict__ sel, const float* __restrict__ wts,
    const int* __restrict__ offsets, int* __restrict__ fill,
    int* __restrict__ etok, float* __restrict__ ewt)
{
  int t = blockIdx.x * 256 + threadIdx.x;
  if (t >= NTOK) return;
  #pragma unroll
  for (int s = 0; s < 2; ++s) {
    int e = sel[t*2 + s];
    int p = atomicAdd(&fill[e], 1);
    etok[offsets[e] + p] = t;
    ewt[offsets[e] + p] = wts[t*2 + s];
  }
}

// ---------------- MoE GEMM1: act = silu(hg@w1[e]) * (hg@w3[e]), gathered rows ----------------
__global__ __launch_bounds__(256) void moe_g1_kernel(
    const float* __restrict__ h2, const float* __restrict__ w1, const float* __restrict__ w3,
    const int* __restrict__ counts, const int* __restrict__ offsets,
    const int* __restrict__ etok, bf16_t* __restrict__ act)
{
  int e = blockIdx.z;
  int cnt = counts[e];
  int mb = blockIdx.y;
  if (mb * 64 >= cnt) return;
  int off = offsets[e];
  const float* W1 = w1 + (size_t)e * HH * IDIM;
  const float* W3 = w3 + (size_t)e * HH * IDIM;
  __shared__ bf16_t As[64][40];
  __shared__ bf16_t B1s[64][40];
  __shared__ bf16_t B3s[64][40];
  int tid = threadIdx.x, lane = tid & 63, wid = tid >> 6;
  int n0 = blockIdx.x * 64;
  const f32x4 fz = {0.f, 0.f, 0.f, 0.f};
  f32x4 acc1[4], acc3[4];
  #pragma unroll
  for (int c = 0; c < 4; ++c) { acc1[c] = fz; acc3[c] = fz; }
  int arow = tid >> 2, ac0 = (tid & 3) * 8;
  int g = mb * 64 + arow;
  int tokA = (g < cnt) ? etok[off + g] : -1;
  int wkk = tid >> 3, wn = (tid & 7) * 8;
  for (int k0 = 0; k0 < HH; k0 += 32) {
    float4 a0 = make_float4(0.f,0.f,0.f,0.f), a1 = make_float4(0.f,0.f,0.f,0.f);
    if (tokA >= 0) {
      const float4* ap = (const float4*)(h2 + (size_t)tokA * HH + k0 + ac0);
      a0 = ap[0]; a1 = ap[1];
    }
    const float4* w1p = (const float4*)(W1 + (size_t)(k0 + wkk) * IDIM + (n0 + wn));
    float4 c0 = w1p[0], c1 = w1p[1];
    const float4* w3p = (const float4*)(W3 + (size_t)(k0 + wkk) * IDIM + (n0 + wn));
    float4 d0 = w3p[0], d1 = w3p[1];
    *(bf16x8*)(&As[arow][ac0]) = cvt_bf16x8(a0, a1);
    float t1[8] = {c0.x,c0.y,c0.z,c0.w,c1.x,c1.y,c1.z,c1.w};
    float t3[8] = {d0.x,d0.y,d0.z,d0.w,d1.x,d1.y,d1.z,d1.w};
    #pragma unroll
    for (int i = 0; i < 8; ++i) { B1s[wn+i][wkk] = (bf16_t)t1[i]; B3s[wn+i][wkk] = (bf16_t)t3[i]; }
    __syncthreads();
    bf16x8 af = *(const bf16x8*)(&As[wid*16 + (lane & 15)][(lane >> 4) * 8]);
    #pragma unroll
    for (int c = 0; c < 4; ++c) {
      bf16x8 b1f = *(const bf16x8*)(&B1s[c*16 + (lane & 15)][(lane >> 4) * 8]);
      acc1[c] = __builtin_amdgcn_mfma_f32_16x16x32_bf16(af, b1f, acc1[c], 0, 0, 0);
      bf16x8 b3f = *(const bf16x8*)(&B3s[c*16 + (lane & 15)][(lane >> 4) * 8]);
      acc3[c] = __builtin_amdgcn_mfma_f32_16x16x32_bf16(af, b3f, acc3[c], 0, 0, 0);
    }
    __syncthreads();
  }
  int rb = wid * 16 + (lane >> 4) * 4;
  int cb = lane & 15;
  #pragma unroll
  for (int c = 0; c < 4; ++c) {
    #pragma unroll
    for (int r = 0; r < 4; ++r) {
      int gg = mb*64 + rb + r;
      if (gg < cnt) {
        float gv = acc1[c][r], uv = acc3[c][r];
        float sv = gv / (1.f + __expf(-gv));
        act[(size_t)(off + gg) * IDIM + (n0 + c*16 + cb)] = (bf16_t)(sv * uv);
      }
    }
  }
}

// ---------------- MoE GEMM2: out[tok] += wgt * (act @ w2[e]) ----------------
__global__ __launch_bounds__(256) void moe_g2_kernel(
    const bf16_t* __restrict__ act, const float* __restrict__ w2,
    const int* __restrict__ counts, const int* __restrict__ offsets,
    const int* __restrict__ etok, const float* __restrict__ ewt,
    float* __restrict__ out)
{
  int e = blockIdx.z;
  int cnt = counts[e];
  int mb = blockIdx.y;
  if (mb * 64 >= cnt) return;
  int off = offsets[e];
  const float* W = w2 + (size_t)e * IDIM * HH;
  __shared__ bf16_t As[64][40];
  __shared__ bf16_t Bs[64][40];
  int tid = threadIdx.x, lane = tid & 63, wid = tid >> 6;
  int n0 = blockIdx.x * 64;
  const f32x4 fz = {0.f, 0.f, 0.f, 0.f};
  f32x4 acc[4]; acc[0]=fz; acc[1]=fz; acc[2]=fz; acc[3]=fz;
  int arow = tid >> 2, ac0 = (tid & 3) * 8;
  int g = mb * 64 + arow;
  bool aok = g < cnt;
  int wkk = tid >> 3, wn = (tid & 7) * 8;
  for (int k0 = 0; k0 < IDIM; k0 += 32) {
    bf16x8 av = { (bf16_t)0.f,(bf16_t)0.f,(bf16_t)0.f,(bf16_t)0.f,
                  (bf16_t)0.f,(bf16_t)0.f,(bf16_t)0.f,(bf16_t)0.f };
    if (aok) av = *(const bf16x8*)(act + (size_t)(off + g) * IDIM + k0 + ac0);
    const float4* wp = (const float4*)(W + (size_t)(k0 + wkk) * HH + (n0 + wn));
    float4 b0 = wp[0], b1 = wp[1];
    *(bf16x8*)(&As[arow][ac0]) = av;
    float tmp[8] = {b0.x,b0.y,b0.z,b0.w,b1.x,b1.y,b1.z,b1.w};
    #pragma unroll
    for (int i = 0; i < 8; ++i) Bs[wn+i][wkk] = (bf16_t)tmp[i];
    __syncthreads();
    bf16x8 af = *(const bf16x8*)(&As[wid*16 + (lane & 15)][(lane >> 4) * 8]);
    #pragma unroll
    for (int c = 0; c < 4; ++c) {
      bf16x8 bf = *(const bf16x8*)(&Bs[c*16 + (lane & 15)][(lane >> 4) * 8]);
      acc[c] = __builtin_amdgcn_mfma_f32_16x16x32_bf16(af, bf, acc[c], 0, 0, 0);
    }
    __syncthreads();
  }
  int rb = wid * 16 + (lane >> 4) * 4;
  int cb = lane & 15;
  #pragma unroll
  for (int c = 0; c < 4; ++c) {
    #pragma unroll
    for (int r = 0; r < 4; ++r) {
      int gg = mb*64 + rb + r;
      if (gg < cnt) {
        int tok = etok[off + gg];
        float wt = ewt[off + gg];
        atomicAdd(&out[(size_t)tok * HH + (n0 + c*16 + cb)], wt * acc[c][r]);
      }
    }
  }
}

extern "C" void kernel_launch(void* const* d_in, const int* in_sizes, int n_in,
                              void* d_out, int out_size, void* d_ws, size_t ws_size,
                              hipStream_t stream)
{
  const float* x    = (const float*)d_in[0];
  const int*   am   = (const int*)d_in[1];
  const int*   pid  = (const int*)d_in[2];
  const float* n1w  = (const float*)d_in[3];
  const float* n2w  = (const float*)d_in[4];
  const float* wq   = (const float*)d_in[5];
  const float* wk   = (const float*)d_in[6];
  const float* wv   = (const float*)d_in[7];
  const float* wo   = (const float*)d_in[8];
  const float* gw   = (const float*)d_in[9];
  const float* w1   = (const float*)d_in[10];
  const float* w3   = (const float*)d_in[11];
  const float* w2   = (const float*)d_in[12];
  float* out = (float*)d_out;
  float* rlogits = out + (size_t)NTOK * HH;

  char* base = (char*)d_ws;
  float* h   = (float*)(base);                    // 16 MB  (norm1 out, later norm2 out)
  float* qb  = (float*)(base + (16u<<20));        // 16 MB
  float* kb  = (float*)(base + (32u<<20));        //  4 MB
  float* vb  = (float*)(base + (36u<<20));        //  4 MB
  float* ob  = (float*)(base + (40u<<20));        // 16 MB
  bf16_t* act = (bf16_t*)(base + (16u<<20));      // 32 MB bf16; aliases qb/kb/vb/ob (dead by then)
  char* sm   = base + (56u<<20);
  int*   sel  = (int*)(sm);
  float* wts  = (float*)(sm + 32768);
  int*   etok = (int*)(sm + 65536);
  float* ewt  = (float*)(sm + 98304);
  int* counts = (int*)(sm + 131072);
  int* offsets = counts + 8;
  int* fill    = counts + 16;

  hipMemsetAsync(counts, 0, 3 * 8 * sizeof(int), stream);

  // attention block
  rmsnorm_kernel<<<NTOK, 256, 0, stream>>>(x, n1w, h);
  gemm_kernel<<<dim3(16, 64), 256, 0, stream>>>(h, wq, nullptr, qb, NHEADS*HDIM, HH);
  gemm_kernel<<<dim3(4, 64), 256, 0, stream>>>(h, wk, nullptr, kb, NKVH*HDIM, HH);
  gemm_kernel<<<dim3(4, 64), 256, 0, stream>>>(h, wv, nullptr, vb, NKVH*HDIM, HH);
  rope_kernel<<<(NTOK*640)/256, 256, 0, stream>>>(qb, kb, pid);
  attn_kernel<<<dim3(SS/16, BB*NHEADS), 256, 0, stream>>>(qb, kb, vb, am, ob);
  gemm_kernel<<<dim3(16, 64), 256, 0, stream>>>(ob, wo, x, out, HH, NHEADS*HDIM);

  // MoE block
  rmsnorm_kernel<<<NTOK, 256, 0, stream>>>(out, n2w, h);
  router_kernel<<<NTOK/4, 256, 0, stream>>>(h, gw, rlogits, sel, wts, counts);
  scan_kernel<<<1, 64, 0, stream>>>(counts, offsets, fill);
  scatter_kernel<<<NTOK/256, 256, 0, stream>>>(sel, wts, offsets, fill, etok, ewt);
  moe_g1_kernel<<<dim3(IDIM/64, 64, NEXP), 256, 0, stream>>>(h, w1, w3, counts, offsets, etok, act);
  moe_g2_kernel<<<dim3(HH/64, 64, NEXP), 256, 0, stream>>>(act, w2, counts, offsets, etok, ewt, out);
}

// Round 3
// 1288.350 us; speedup vs baseline: 1.8617x; 1.8617x over previous
//
#include <hip/hip_runtime.h>
#include <cstdint>
#include <cstddef>

#define BB 2
#define SS 2048
#define HH 1024
#define NHEADS 16
#define NKVH 4
#define HDIM 64
#define NEXP 8
#define IDIM 2048
#define NTOK (BB*SS)

typedef __bf16 bf16_t;
typedef bf16_t bf16x8 __attribute__((ext_vector_type(8)));
typedef bf16_t bf16x4 __attribute__((ext_vector_type(4)));
typedef float f32x4 __attribute__((ext_vector_type(4)));

static __device__ __forceinline__ bf16x8 cvt_bf16x8(float4 a, float4 b) {
  bf16x8 r = { (bf16_t)a.x, (bf16_t)a.y, (bf16_t)a.z, (bf16_t)a.w,
               (bf16_t)b.x, (bf16_t)b.y, (bf16_t)b.z, (bf16_t)b.w };
  return r;
}

// ---------------- RMSNorm: one block per token ----------------
__global__ __launch_bounds__(256) void rmsnorm_kernel(
    const float* __restrict__ x, const float* __restrict__ w, float* __restrict__ out)
{
  int t = blockIdx.x;
  int tid = threadIdx.x;
  float4 v = ((const float4*)(x + (size_t)t * HH))[tid];
  float ss = v.x*v.x + v.y*v.y + v.z*v.z + v.w*v.w;
  #pragma unroll
  for (int off = 32; off > 0; off >>= 1) ss += __shfl_xor(ss, off);
  __shared__ float red[4];
  if ((tid & 63) == 0) red[tid >> 6] = ss;
  __syncthreads();
  float tot = red[0] + red[1] + red[2] + red[3];
  float scale = 1.0f / sqrtf(tot / (float)HH + 1e-6f);
  float4 wv = ((const float4*)w)[tid];
  float4 o;
  o.x = v.x * scale * wv.x;
  o.y = v.y * scale * wv.y;
  o.z = v.z * scale * wv.z;
  o.w = v.w * scale * wv.w;
  ((float4*)(out + (size_t)t * HH))[tid] = o;
}

// ---------------- generic bf16-MFMA GEMM: C[M,N] = A[M,K]@W[K,N] (+R) ----------------
__global__ __launch_bounds__(256) void gemm_kernel(
    const float* __restrict__ A, const float* __restrict__ W,
    const float* __restrict__ R, float* __restrict__ C,
    int N, int K)
{
  __shared__ bf16_t As[64][40];
  __shared__ bf16_t Bs[64][40];
  int tid = threadIdx.x;
  int lane = tid & 63, wid = tid >> 6;
  int m0 = blockIdx.y * 64, n0 = blockIdx.x * 64;
  const f32x4 fz = {0.f, 0.f, 0.f, 0.f};
  f32x4 acc[4]; acc[0]=fz; acc[1]=fz; acc[2]=fz; acc[3]=fz;
  int arow = tid >> 2, ac0 = (tid & 3) * 8;
  int wkk = tid >> 3, wn = (tid & 7) * 8;
  for (int k0 = 0; k0 < K; k0 += 32) {
    const float4* ap = (const float4*)(A + (size_t)(m0 + arow) * K + (k0 + ac0));
    float4 a0 = ap[0], a1 = ap[1];
    const float4* wp = (const float4*)(W + (size_t)(k0 + wkk) * N + (n0 + wn));
    float4 b0 = wp[0], b1 = wp[1];
    *(bf16x8*)(&As[arow][ac0]) = cvt_bf16x8(a0, a1);
    float tmp[8] = {b0.x,b0.y,b0.z,b0.w,b1.x,b1.y,b1.z,b1.w};
    #pragma unroll
    for (int i = 0; i < 8; ++i) Bs[wn + i][wkk] = (bf16_t)tmp[i];
    __syncthreads();
    bf16x8 af = *(const bf16x8*)(&As[wid*16 + (lane & 15)][(lane >> 4) * 8]);
    #pragma unroll
    for (int c = 0; c < 4; ++c) {
      bf16x8 bf = *(const bf16x8*)(&Bs[c*16 + (lane & 15)][(lane >> 4) * 8]);
      acc[c] = __builtin_amdgcn_mfma_f32_16x16x32_bf16(af, bf, acc[c], 0, 0, 0);
    }
    __syncthreads();
  }
  int rb = wid * 16 + (lane >> 4) * 4;
  int cb = lane & 15;
  #pragma unroll
  for (int c = 0; c < 4; ++c) {
    #pragma unroll
    for (int r = 0; r < 4; ++r) {
      size_t off = (size_t)(m0 + rb + r) * N + (n0 + c*16 + cb);
      float vv = acc[c][r];
      C[off] = R ? vv + R[off] : vv;
    }
  }
}

// ---------------- RoPE (in-place on q and k) ----------------
__global__ __launch_bounds__(256) void rope_kernel(
    float* __restrict__ q, float* __restrict__ k, const int* __restrict__ pos_ids)
{
  int idx = blockIdx.x * 256 + threadIdx.x;
  int token = idx / 640;
  int rem = idx - token * 640;
  int head = rem >> 5;
  int i = rem & 31;
  float pos = (float)pos_ids[token];
  float inv = __expf(-(float)i * (9.210340371976184f / 32.0f));
  float ang = pos * inv;
  float s, c;
  sincosf(ang, &s, &c);
  float* p;
  if (head < NHEADS) p = q + (size_t)token * (NHEADS*HDIM) + head * HDIM;
  else               p = k + (size_t)token * (NKVH*HDIM) + (head - NHEADS) * HDIM;
  float x1 = p[i], x2 = p[i + 32];
  p[i]      = x1 * c - x2 * s;
  p[i + 32] = x2 * c + x1 * s;
}

// ---------------- causal GQA flash attention, split-precision bf16 MFMA ----------------
// hi/lo bf16 decomposition of Q,K,P,V; S = qh*kh + qh*kl + ql*kh (rel err ~2^-17).
// 4 waves, 64 q-rows/block, K/V chunks of 64. K staged [key][d]; V transposed [d][key].
__global__ __launch_bounds__(256) void attn_mfma_kernel(
    const float* __restrict__ q, const float* __restrict__ k, const float* __restrict__ v,
    const int* __restrict__ amask, float* __restrict__ out)
{
  __shared__ bf16_t Khi[64][72];
  __shared__ bf16_t Klo[64][72];
  __shared__ bf16_t Vhi[64][72];
  __shared__ bf16_t Vlo[64][72];
  __shared__ bf16_t Phi[4][16][72];
  __shared__ bf16_t Plo[4][16][72];
  __shared__ float ms[64];
  int tid = threadIdx.x, lane = tid & 63, w = tid >> 6;
  int l4 = lane & 15, g = lane >> 4;
  int bh = blockIdx.y;
  int b = bh >> 4, h = bh & 15, kvh = h >> 2;
  int qb = gridDim.x - 1 - blockIdx.x;   // heavy blocks first
  int r0 = qb * 64;

  // Q hi/lo fragments (A operand), pre-scaled by 1/sqrt(HD)
  bf16x8 qh[2], ql[2];
  {
    const float* qp = q + (size_t)(b*SS + r0 + w*16 + l4) * (NHEADS*HDIM) + h*HDIM + g*8;
    #pragma unroll
    for (int st = 0; st < 2; ++st) {
      float4 t0 = *(const float4*)(qp + st*32);
      float4 t1 = *(const float4*)(qp + st*32 + 4);
      float f[8] = {t0.x*0.125f, t0.y*0.125f, t0.z*0.125f, t0.w*0.125f,
                    t1.x*0.125f, t1.y*0.125f, t1.z*0.125f, t1.w*0.125f};
      #pragma unroll
      for (int j = 0; j < 8; ++j) {
        bf16_t hi = (bf16_t)f[j];
        qh[st][j] = hi;
        ql[st][j] = (bf16_t)(f[j] - (float)hi);
      }
    }
  }
  const f32x4 fz = {0.f,0.f,0.f,0.f};
  f32x4 o[4]; o[0]=fz; o[1]=fz; o[2]=fz; o[3]=fz;
  float mrow[4] = {-3e38f,-3e38f,-3e38f,-3e38f};
  float lrow[4] = {0.f,0.f,0.f,0.f};

  int vkey = tid & 63;
  int dvb = (tid >> 6) * 16;
  int nch = qb + 1;
  for (int ch = 0; ch < nch; ++ch) {
    int kc = ch * 64;
    __syncthreads();
    #pragma unroll
    for (int it = 0; it < 4; ++it) {
      int slot = it*256 + tid;
      int key = slot >> 4, dq = (slot & 15) * 4;
      float4 kk4 = *(const float4*)(k + (size_t)(b*SS + kc + key)*(NKVH*HDIM) + kvh*HDIM + dq);
      bf16_t kh0 = (bf16_t)kk4.x, kh1 = (bf16_t)kk4.y, kh2 = (bf16_t)kk4.z, kh3 = (bf16_t)kk4.w;
      bf16x4 khv = {kh0, kh1, kh2, kh3};
      bf16x4 klv = { (bf16_t)(kk4.x-(float)kh0), (bf16_t)(kk4.y-(float)kh1),
                     (bf16_t)(kk4.z-(float)kh2), (bf16_t)(kk4.w-(float)kh3) };
      *(bf16x4*)&Khi[key][dq] = khv;
      *(bf16x4*)&Klo[key][dq] = klv;
      int dv = dvb + it*4;
      float4 vv4 = *(const float4*)(v + (size_t)(b*SS + kc + vkey)*(NKVH*HDIM) + kvh*HDIM + dv);
      float vf4[4] = {vv4.x, vv4.y, vv4.z, vv4.w};
      #pragma unroll
      for (int j = 0; j < 4; ++j) {
        bf16_t hi = (bf16_t)vf4[j];
        Vhi[dv+j][vkey] = hi;
        Vlo[dv+j][vkey] = (bf16_t)(vf4[j] - (float)hi);
      }
    }
    if (tid < 64) ms[tid] = (amask[b*SS + kc + tid] > 0) ? 0.f : -3e38f;
    __syncthreads();
    // S = Q @ K^T, split: qh*kh + qh*kl + ql*kh
    f32x4 s[4]; s[0]=fz; s[1]=fz; s[2]=fz; s[3]=fz;
    #pragma unroll
    for (int st = 0; st < 2; ++st) {
      #pragma unroll
      for (int c = 0; c < 4; ++c) {
        bf16x8 kfh = *(const bf16x8*)&Khi[c*16 + l4][st*32 + g*8];
        bf16x8 kfl = *(const bf16x8*)&Klo[c*16 + l4][st*32 + g*8];
        s[c] = __builtin_amdgcn_mfma_f32_16x16x32_bf16(qh[st], kfh, s[c], 0, 0, 0);
        s[c] = __builtin_amdgcn_mfma_f32_16x16x32_bf16(qh[st], kfl, s[c], 0, 0, 0);
        s[c] = __builtin_amdgcn_mfma_f32_16x16x32_bf16(ql[st], kfh, s[c], 0, 0, 0);
      }
    }
    // mask
    #pragma unroll
    for (int c = 0; c < 4; ++c) {
      int kg = kc + c*16 + l4;
      float mk = ms[c*16 + l4];
      #pragma unroll
      for (int r = 0; r < 4; ++r) {
        int rowg = r0 + w*16 + g*4 + r;
        float sv = s[c][r] + mk;
        s[c][r] = (kg <= rowg) ? sv : -3e38f;
      }
    }
    // online softmax (row stats across the 16-lane col group)
    float mnew[4], alpha[4];
    #pragma unroll
    for (int r = 0; r < 4; ++r) {
      float mc = fmaxf(fmaxf(s[0][r], s[1][r]), fmaxf(s[2][r], s[3][r]));
      mc = fmaxf(mc, __shfl_xor(mc, 1));
      mc = fmaxf(mc, __shfl_xor(mc, 2));
      mc = fmaxf(mc, __shfl_xor(mc, 4));
      mc = fmaxf(mc, __shfl_xor(mc, 8));
      mnew[r] = fmaxf(mrow[r], mc);
      alpha[r] = __expf(mrow[r] - mnew[r]);
      mrow[r] = mnew[r];
    }
    float rsum[4] = {0.f,0.f,0.f,0.f};
    #pragma unroll
    for (int c = 0; c < 4; ++c) {
      #pragma unroll
      for (int r = 0; r < 4; ++r) {
        float p = __expf(s[c][r] - mnew[r]);
        s[c][r] = p;
        rsum[r] += p;
      }
    }
    #pragma unroll
    for (int r = 0; r < 4; ++r) {
      float t = rsum[r];
      t += __shfl_xor(t, 1); t += __shfl_xor(t, 2);
      t += __shfl_xor(t, 4); t += __shfl_xor(t, 8);
      lrow[r] = lrow[r] * alpha[r] + t;
      o[0][r] *= alpha[r]; o[1][r] *= alpha[r]; o[2][r] *= alpha[r]; o[3][r] *= alpha[r];
    }
    // P hi/lo: C-layout -> A-layout via per-wave LDS
    #pragma unroll
    for (int c = 0; c < 4; ++c) {
      #pragma unroll
      for (int r = 0; r < 4; ++r) {
        float p = s[c][r];
        bf16_t hi = (bf16_t)p;
        Phi[w][g*4 + r][c*16 + l4] = hi;
        Plo[w][g*4 + r][c*16 + l4] = (bf16_t)(p - (float)hi);
      }
    }
    __syncthreads();
    // O += P @ V, split: ph*vh + pl*vh + ph*vl
    #pragma unroll
    for (int st = 0; st < 2; ++st) {
      bf16x8 pfh = *(const bf16x8*)&Phi[w][l4][st*32 + g*8];
      bf16x8 pfl = *(const bf16x8*)&Plo[w][l4][st*32 + g*8];
      #pragma unroll
      for (int c = 0; c < 4; ++c) {
        bf16x8 vfh = *(const bf16x8*)&Vhi[c*16 + l4][st*32 + g*8];
        bf16x8 vfl = *(const bf16x8*)&Vlo[c*16 + l4][st*32 + g*8];
        o[c] = __builtin_amdgcn_mfma_f32_16x16x32_bf16(pfh, vfh, o[c], 0, 0, 0);
        o[c] = __builtin_amdgcn_mfma_f32_16x16x32_bf16(pfl, vfh, o[c], 0, 0, 0);
        o[c] = __builtin_amdgcn_mfma_f32_16x16x32_bf16(pfh, vfl, o[c], 0, 0, 0);
      }
    }
  }
  #pragma unroll
  for (int r = 0; r < 4; ++r) {
    float inv = (lrow[r] > 0.f) ? 1.f / lrow[r] : 0.f;
    int row = r0 + w*16 + g*4 + r;
    float* op = out + (size_t)(b*SS + row) * (NHEADS*HDIM) + h*HDIM;
    #pragma unroll
    for (int c = 0; c < 4; ++c)
      op[c*16 + l4] = o[c][r] * inv;
  }
}

// ---------------- router ----------------
__global__ __launch_bounds__(256) void router_kernel(
    const float* __restrict__ h2, const float* __restrict__ gw,
    float* __restrict__ logits_out, int* __restrict__ sel, float* __restrict__ wts,
    int* __restrict__ counts)
{
  int tid = threadIdx.x, lane = tid & 63, w = tid >> 6;
  int tok = blockIdx.x * 4 + w;
  float acc[NEXP] = {0.f,0.f,0.f,0.f,0.f,0.f,0.f,0.f};
  const float* xr = h2 + (size_t)tok * HH;
  for (int hh = lane; hh < HH; hh += 64) {
    float xv = xr[hh];
    const float* gr = gw + (size_t)hh * NEXP;
    #pragma unroll
    for (int e = 0; e < NEXP; ++e) acc[e] += xv * gr[e];
  }
  #pragma unroll
  for (int e = 0; e < NEXP; ++e) {
    #pragma unroll
    for (int off = 32; off > 0; off >>= 1) acc[e] += __shfl_xor(acc[e], off);
  }
  if (lane == 0) {
    float* lo = logits_out + (size_t)tok * NEXP;
    #pragma unroll
    for (int e = 0; e < NEXP; ++e) lo[e] = acc[e];
    int b0 = 0; float v0 = acc[0];
    #pragma unroll
    for (int e = 1; e < NEXP; ++e) if (acc[e] > v0) { v0 = acc[e]; b0 = e; }
    int b1 = -1; float v1 = -1e38f;
    #pragma unroll
    for (int e = 0; e < NEXP; ++e) if (e != b0 && acc[e] > v1) { v1 = acc[e]; b1 = e; }
    float wa = 1.f / (1.f + __expf(v1 - v0));
    sel[tok*2] = b0; sel[tok*2+1] = b1;
    wts[tok*2] = wa; wts[tok*2+1] = 1.f - wa;
    atomicAdd(&counts[b0], 1);
    atomicAdd(&counts[b1], 1);
  }
}

__global__ void scan_kernel(const int* __restrict__ counts, int* __restrict__ offsets,
                            int* __restrict__ fill)
{
  if (threadIdx.x == 0 && blockIdx.x == 0) {
    int o = 0;
    for (int e = 0; e < NEXP; ++e) { offsets[e] = o; o += counts[e]; fill[e] = 0; }
  }
}

__global__ __launch_bounds__(256) void scatter_kernel(
    const int* __restrict__ sel, const float* __restrict__ wts,
    const int* __restrict__ offsets, int* __restrict__ fill,
    int* __restrict__ etok, float* __restrict__ ewt)
{
  int t = blockIdx.x * 256 + threadIdx.x;
  if (t >= NTOK) return;
  #pragma unroll
  for (int s = 0; s < 2; ++s) {
    int e = sel[t*2 + s];
    int p = atomicAdd(&fill[e], 1);
    etok[offsets[e] + p] = t;
    ewt[offsets[e] + p] = wts[t*2 + s];
  }
}

// ---------------- MoE GEMM1 ----------------
__global__ __launch_bounds__(256) void moe_g1_kernel(
    const float* __restrict__ h2, const float* __restrict__ w1, const float* __restrict__ w3,
    const int* __restrict__ counts, const int* __restrict__ offsets,
    const int* __restrict__ etok, bf16_t* __restrict__ act)
{
  int e = blockIdx.z;
  int cnt = counts[e];
  int mb = blockIdx.y;
  if (mb * 64 >= cnt) return;
  int off = offsets[e];
  const float* W1 = w1 + (size_t)e * HH * IDIM;
  const float* W3 = w3 + (size_t)e * HH * IDIM;
  __shared__ bf16_t As[64][40];
  __shared__ bf16_t B1s[64][40];
  __shared__ bf16_t B3s[64][40];
  int tid = threadIdx.x, lane = tid & 63, wid = tid >> 6;
  int n0 = blockIdx.x * 64;
  const f32x4 fz = {0.f, 0.f, 0.f, 0.f};
  f32x4 acc1[4], acc3[4];
  #pragma unroll
  for (int c = 0; c < 4; ++c) { acc1[c] = fz; acc3[c] = fz; }
  int arow = tid >> 2, ac0 = (tid & 3) * 8;
  int g = mb * 64 + arow;
  int tokA = (g < cnt) ? etok[off + g] : -1;
  int wkk = tid >> 3, wn = (tid & 7) * 8;
  for (int k0 = 0; k0 < HH; k0 += 32) {
    float4 a0 = make_float4(0.f,0.f,0.f,0.f), a1 = make_float4(0.f,0.f,0.f,0.f);
    if (tokA >= 0) {
      const float4* ap = (const float4*)(h2 + (size_t)tokA * HH + k0 + ac0);
      a0 = ap[0]; a1 = ap[1];
    }
    const float4* w1p = (const float4*)(W1 + (size_t)(k0 + wkk) * IDIM + (n0 + wn));
    float4 c0 = w1p[0], c1 = w1p[1];
    const float4* w3p = (const float4*)(W3 + (size_t)(k0 + wkk) * IDIM + (n0 + wn));
    float4 d0 = w3p[0], d1 = w3p[1];
    *(bf16x8*)(&As[arow][ac0]) = cvt_bf16x8(a0, a1);
    float t1[8] = {c0.x,c0.y,c0.z,c0.w,c1.x,c1.y,c1.z,c1.w};
    float t3[8] = {d0.x,d0.y,d0.z,d0.w,d1.x,d1.y,d1.z,d1.w};
    #pragma unroll
    for (int i = 0; i < 8; ++i) { B1s[wn+i][wkk] = (bf16_t)t1[i]; B3s[wn+i][wkk] = (bf16_t)t3[i]; }
    __syncthreads();
    bf16x8 af = *(const bf16x8*)(&As[wid*16 + (lane & 15)][(lane >> 4) * 8]);
    #pragma unroll
    for (int c = 0; c < 4; ++c) {
      bf16x8 b1f = *(const bf16x8*)(&B1s[c*16 + (lane & 15)][(lane >> 4) * 8]);
      acc1[c] = __builtin_amdgcn_mfma_f32_16x16x32_bf16(af, b1f, acc1[c], 0, 0, 0);
      bf16x8 b3f = *(const bf16x8*)(&B3s[c*16 + (lane & 15)][(lane >> 4) * 8]);
      acc3[c] = __builtin_amdgcn_mfma_f32_16x16x32_bf16(af, b3f, acc3[c], 0, 0, 0);
    }
    __syncthreads();
  }
  int rb = wid * 16 + (lane >> 4) * 4;
  int cb = lane & 15;
  #pragma unroll
  for (int c = 0; c < 4; ++c) {
    #pragma unroll
    for (int r = 0; r < 4; ++r) {
      int gg = mb*64 + rb + r;
      if (gg < cnt) {
        float gv = acc1[c][r], uv = acc3[c][r];
        float sv = gv / (1.f + __expf(-gv));
        act[(size_t)(off + gg) * IDIM + (n0 + c*16 + cb)] = (bf16_t)(sv * uv);
      }
    }
  }
}

// ---------------- MoE GEMM2 ----------------
__global__ __launch_bounds__(256) void moe_g2_kernel(
    const bf16_t* __restrict__ act, const float* __restrict__ w2,
    const int* __restrict__ counts, const int* __restrict__ offsets,
    const int* __restrict__ etok, const float* __restrict__ ewt,
    float* __restrict__ out)
{
  int e = blockIdx.z;
  int cnt = counts[e];
  int mb = blockIdx.y;
  if (mb * 64 >= cnt) return;
  int off = offsets[e];
  const float* W = w2 + (size_t)e * IDIM * HH;
  __shared__ bf16_t As[64][40];
  __shared__ bf16_t Bs[64][40];
  int tid = threadIdx.x, lane = tid & 63, wid = tid >> 6;
  int n0 = blockIdx.x * 64;
  const f32x4 fz = {0.f, 0.f, 0.f, 0.f};
  f32x4 acc[4]; acc[0]=fz; acc[1]=fz; acc[2]=fz; acc[3]=fz;
  int arow = tid >> 2, ac0 = (tid & 3) * 8;
  int g = mb * 64 + arow;
  bool aok = g < cnt;
  int wkk = tid >> 3, wn = (tid & 7) * 8;
  for (int k0 = 0; k0 < IDIM; k0 += 32) {
    bf16x8 av = { (bf16_t)0.f,(bf16_t)0.f,(bf16_t)0.f,(bf16_t)0.f,
                  (bf16_t)0.f,(bf16_t)0.f,(bf16_t)0.f,(bf16_t)0.f };
    if (aok) av = *(const bf16x8*)(act + (size_t)(off + g) * IDIM + k0 + ac0);
    const float4* wp = (const float4*)(W + (size_t)(k0 + wkk) * HH + (n0 + wn));
    float4 b0 = wp[0], b1 = wp[1];
    *(bf16x8*)(&As[arow][ac0]) = av;
    float tmp[8] = {b0.x,b0.y,b0.z,b0.w,b1.x,b1.y,b1.z,b1.w};
    #pragma unroll
    for (int i = 0; i < 8; ++i) Bs[wn+i][wkk] = (bf16_t)tmp[i];
    __syncthreads();
    bf16x8 af = *(const bf16x8*)(&As[wid*16 + (lane & 15)][(lane >> 4) * 8]);
    #pragma unroll
    for (int c = 0; c < 4; ++c) {
      bf16x8 bf = *(const bf16x8*)(&Bs[c*16 + (lane & 15)][(lane >> 4) * 8]);
      acc[c] = __builtin_amdgcn_mfma_f32_16x16x32_bf16(af, bf, acc[c], 0, 0, 0);
    }
    __syncthreads();
  }
  int rb = wid * 16 + (lane >> 4) * 4;
  int cb = lane & 15;
  #pragma unroll
  for (int c = 0; c < 4; ++c) {
    #pragma unroll
    for (int r = 0; r < 4; ++r) {
      int gg = mb*64 + rb + r;
      if (gg < cnt) {
        int tok = etok[off + gg];
        float wt = ewt[off + gg];
        atomicAdd(&out[(size_t)tok * HH + (n0 + c*16 + cb)], wt * acc[c][r]);
      }
    }
  }
}

extern "C" void kernel_launch(void* const* d_in, const int* in_sizes, int n_in,
                              void* d_out, int out_size, void* d_ws, size_t ws_size,
                              hipStream_t stream)
{
  const float* x    = (const float*)d_in[0];
  const int*   am   = (const int*)d_in[1];
  const int*   pid  = (const int*)d_in[2];
  const float* n1w  = (const float*)d_in[3];
  const float* n2w  = (const float*)d_in[4];
  const float* wq   = (const float*)d_in[5];
  const float* wk   = (const float*)d_in[6];
  const float* wv   = (const float*)d_in[7];
  const float* wo   = (const float*)d_in[8];
  const float* gw   = (const float*)d_in[9];
  const float* w1   = (const float*)d_in[10];
  const float* w3   = (const float*)d_in[11];
  const float* w2   = (const float*)d_in[12];
  float* out = (float*)d_out;
  float* rlogits = out + (size_t)NTOK * HH;

  char* base = (char*)d_ws;
  float* h   = (float*)(base);
  float* qb  = (float*)(base + (16u<<20));
  float* kb  = (float*)(base + (32u<<20));
  float* vb  = (float*)(base + (36u<<20));
  float* ob  = (float*)(base + (40u<<20));
  bf16_t* act = (bf16_t*)(base + (16u<<20));
  char* sm   = base + (56u<<20);
  int*   sel  = (int*)(sm);
  float* wts  = (float*)(sm + 32768);
  int*   etok = (int*)(sm + 65536);
  float* ewt  = (float*)(sm + 98304);
  int* counts = (int*)(sm + 131072);
  int* offsets = counts + 8;
  int* fill    = counts + 16;

  hipMemsetAsync(counts, 0, 3 * 8 * sizeof(int), stream);

  // attention block
  rmsnorm_kernel<<<NTOK, 256, 0, stream>>>(x, n1w, h);
  gemm_kernel<<<dim3(16, 64), 256, 0, stream>>>(h, wq, nullptr, qb, NHEADS*HDIM, HH);
  gemm_kernel<<<dim3(4, 64), 256, 0, stream>>>(h, wk, nullptr, kb, NKVH*HDIM, HH);
  gemm_kernel<<<dim3(4, 64), 256, 0, stream>>>(h, wv, nullptr, vb, NKVH*HDIM, HH);
  rope_kernel<<<(NTOK*640)/256, 256, 0, stream>>>(qb, kb, pid);
  attn_mfma_kernel<<<dim3(SS/64, BB*NHEADS), 256, 0, stream>>>(qb, kb, vb, am, ob);
  gemm_kernel<<<dim3(16, 64), 256, 0, stream>>>(ob, wo, x, out, HH, NHEADS*HDIM);

  // MoE block
  rmsnorm_kernel<<<NTOK, 256, 0, stream>>>(out, n2w, h);
  router_kernel<<<NTOK/4, 256, 0, stream>>>(h, gw, rlogits, sel, wts, counts);
  scan_kernel<<<1, 64, 0, stream>>>(counts, offsets, fill);
  scatter_kernel<<<NTOK/256, 256, 0, stream>>>(sel, wts, offsets, fill, etok, ewt);
  moe_g1_kernel<<<dim3(IDIM/64, 64, NEXP), 256, 0, stream>>>(h, w1, w3, counts, offsets, etok, act);
  moe_g2_kernel<<<dim3(HH/64, 64, NEXP), 256, 0, stream>>>(act, w2, counts, offsets, etok, ewt, out);
}

// Round 4
// 1025.600 us; speedup vs baseline: 2.3387x; 1.2562x over previous
//
#include <hip/hip_runtime.h>
#include <cstdint>
#include <cstddef>

#define BB 2
#define SS 2048
#define HH 1024
#define NHEADS 16
#define NKVH 4
#define HDIM 64
#define NEXP 8
#define IDIM 2048
#define NTOK (BB*SS)

typedef __bf16 bf16_t;
typedef bf16_t bf16x8 __attribute__((ext_vector_type(8)));
typedef bf16_t bf16x4 __attribute__((ext_vector_type(4)));
typedef float f32x4 __attribute__((ext_vector_type(4)));

// async global->LDS, 16B per lane; LDS dest = wave-uniform base + lane*16
static __device__ __forceinline__ void gl16(const void* g, void* l) {
  __builtin_amdgcn_global_load_lds(
      (const __attribute__((address_space(1))) unsigned int*)g,
      (__attribute__((address_space(3))) unsigned int*)l, 16, 0, 0);
}

// ---------------- weight transpose+convert: W fp32 [K][N] -> WT bf16 [N][K] ----------------
__global__ __launch_bounds__(256) void transpose_cvt(
    const float* __restrict__ W, bf16_t* __restrict__ WT, int K, int N)
{
  const float* Wm = W + (size_t)blockIdx.z * K * N;
  bf16_t* Tm = WT + (size_t)blockIdx.z * K * N;
  __shared__ float Ls[64][65];
  int tid = threadIdx.x;
  int k0 = blockIdx.y * 64, n0 = blockIdx.x * 64;
  int rr = tid >> 4, cc = (tid & 15) * 4;
  #pragma unroll
  for (int rep = 0; rep < 4; ++rep) {
    float4 vv = *(const float4*)(Wm + (size_t)(k0 + rep*16 + rr) * N + n0 + cc);
    Ls[rep*16 + rr][cc+0] = vv.x;
    Ls[rep*16 + rr][cc+1] = vv.y;
    Ls[rep*16 + rr][cc+2] = vv.z;
    Ls[rep*16 + rr][cc+3] = vv.w;
  }
  __syncthreads();
  int nn = tid >> 2, ks = (tid & 3) * 16;
  bf16x8 o0, o1;
  #pragma unroll
  for (int j = 0; j < 8; ++j) o0[j] = (bf16_t)Ls[ks + j][nn];
  #pragma unroll
  for (int j = 0; j < 8; ++j) o1[j] = (bf16_t)Ls[ks + 8 + j][nn];
  bf16_t* op = Tm + (size_t)(n0 + nn) * K + k0 + ks;
  *(bf16x8*)op = o0;
  *(bf16x8*)(op + 8) = o1;
}

// ---------------- RMSNorm: fp32 in, optional fp32 out + bf16 out ----------------
__global__ __launch_bounds__(256) void rmsnorm_kernel(
    const float* __restrict__ x, const float* __restrict__ w,
    float* __restrict__ outf, bf16_t* __restrict__ outb)
{
  int t = blockIdx.x;
  int tid = threadIdx.x;
  float4 v = ((const float4*)(x + (size_t)t * HH))[tid];
  float ss = v.x*v.x + v.y*v.y + v.z*v.z + v.w*v.w;
  #pragma unroll
  for (int off = 32; off > 0; off >>= 1) ss += __shfl_xor(ss, off);
  __shared__ float red[4];
  if ((tid & 63) == 0) red[tid >> 6] = ss;
  __syncthreads();
  float tot = red[0] + red[1] + red[2] + red[3];
  float scale = 1.0f / sqrtf(tot / (float)HH + 1e-6f);
  float4 wv = ((const float4*)w)[tid];
  float4 o;
  o.x = v.x * scale * wv.x;
  o.y = v.y * scale * wv.y;
  o.z = v.z * scale * wv.z;
  o.w = v.w * scale * wv.w;
  if (outf) ((float4*)(outf + (size_t)t * HH))[tid] = o;
  bf16x4 ob4 = { (bf16_t)o.x, (bf16_t)o.y, (bf16_t)o.z, (bf16_t)o.w };
  *(bf16x4*)(outb + (size_t)t * HH + tid*4) = ob4;
}

// ---------------- m97-style GEMM: C[M,N] fp32 = A_bf16[M,K] @ Bt_bf16[N,K] (+R) ----------------
// 128x128 tile, BK=32, 4 waves in 2x2 quadrants, global_load_lds staging.
__global__ __launch_bounds__(256) void gemm_bt(
    const bf16_t* __restrict__ A, const bf16_t* __restrict__ Bt,
    const float* __restrict__ R, float* __restrict__ C, int N, int K)
{
  __shared__ __align__(16) bf16_t As[4096];   // [128][32]
  __shared__ __align__(16) bf16_t Bs[4096];
  int tid = threadIdx.x, lane = tid & 63, w = tid >> 6;
  int l4 = lane & 15, g = lane >> 4;
  int m0 = blockIdx.y * 128, n0 = blockIdx.x * 128;
  int lrow = w*16 + (lane >> 2), lk = (lane & 3) * 8;
  const bf16_t* ag0 = A + (size_t)(m0 + lrow) * K + lk;
  const bf16_t* ag1 = ag0 + (size_t)64 * K;
  const bf16_t* bg0 = Bt + (size_t)(n0 + lrow) * K + lk;
  const bf16_t* bg1 = bg0 + (size_t)64 * K;
  bf16_t* lA0 = As + w*512;  bf16_t* lA1 = As + 2048 + w*512;
  bf16_t* lB0 = Bs + w*512;  bf16_t* lB1 = Bs + 2048 + w*512;
  const f32x4 fz = {0.f,0.f,0.f,0.f};
  f32x4 acc[4][4];
  #pragma unroll
  for (int i = 0; i < 4; ++i) { acc[i][0]=fz; acc[i][1]=fz; acc[i][2]=fz; acc[i][3]=fz; }
  int wm = (w >> 1) * 64, wn = (w & 1) * 64;
  for (int k0 = 0; k0 < K; k0 += 32) {
    __syncthreads();
    gl16(ag0, lA0); gl16(ag1, lA1); gl16(bg0, lB0); gl16(bg1, lB1);
    ag0 += 32; ag1 += 32; bg0 += 32; bg1 += 32;
    __syncthreads();
    bf16x8 af[4], bfr[4];
    #pragma unroll
    for (int mi = 0; mi < 4; ++mi) af[mi] = *(const bf16x8*)&As[(wm + mi*16 + l4)*32 + g*8];
    #pragma unroll
    for (int ni = 0; ni < 4; ++ni) bfr[ni] = *(const bf16x8*)&Bs[(wn + ni*16 + l4)*32 + g*8];
    #pragma unroll
    for (int mi = 0; mi < 4; ++mi)
      #pragma unroll
      for (int ni = 0; ni < 4; ++ni)
        acc[mi][ni] = __builtin_amdgcn_mfma_f32_16x16x32_bf16(af[mi], bfr[ni], acc[mi][ni], 0, 0, 0);
  }
  #pragma unroll
  for (int mi = 0; mi < 4; ++mi) {
    int rowb = m0 + wm + mi*16 + g*4;
    #pragma unroll
    for (int r = 0; r < 4; ++r) {
      size_t rb = (size_t)(rowb + r) * N;
      #pragma unroll
      for (int ni = 0; ni < 4; ++ni) {
        int col = n0 + wn + ni*16 + l4;
        float vv = acc[mi][ni][r];
        C[rb + col] = R ? vv + R[rb + col] : vv;
      }
    }
  }
}

// ---------------- RoPE (in-place on q and k) ----------------
__global__ __launch_bounds__(256) void rope_kernel(
    float* __restrict__ q, float* __restrict__ k, const int* __restrict__ pos_ids)
{
  int idx = blockIdx.x * 256 + threadIdx.x;
  int token = idx / 640;
  int rem = idx - token * 640;
  int head = rem >> 5;
  int i = rem & 31;
  float pos = (float)pos_ids[token];
  float inv = __expf(-(float)i * (9.210340371976184f / 32.0f));
  float ang = pos * inv;
  float s, c;
  sincosf(ang, &s, &c);
  float* p;
  if (head < NHEADS) p = q + (size_t)token * (NHEADS*HDIM) + head * HDIM;
  else               p = k + (size_t)token * (NKVH*HDIM) + (head - NHEADS) * HDIM;
  float x1 = p[i], x2 = p[i + 32];
  p[i]      = x1 * c - x2 * s;
  p[i + 32] = x2 * c + x1 * s;
}

// ---------------- causal GQA flash attention, split-precision bf16 MFMA ----------------
__global__ __launch_bounds__(256) void attn_mfma_kernel(
    const float* __restrict__ q, const float* __restrict__ k, const float* __restrict__ v,
    const int* __restrict__ amask, bf16_t* __restrict__ out)
{
  __shared__ bf16_t Khi[64][72];
  __shared__ bf16_t Klo[64][72];
  __shared__ bf16_t Vhi[64][72];
  __shared__ bf16_t Vlo[64][72];
  __shared__ bf16_t Phi[4][16][72];
  __shared__ bf16_t Plo[4][16][72];
  __shared__ float ms[64];
  int tid = threadIdx.x, lane = tid & 63, w = tid >> 6;
  int l4 = lane & 15, g = lane >> 4;
  int bh = blockIdx.y;
  int b = bh >> 4, h = bh & 15, kvh = h >> 2;
  int qb = gridDim.x - 1 - blockIdx.x;   // heavy blocks first
  int r0 = qb * 64;

  bf16x8 qh[2], ql[2];
  {
    const float* qp = q + (size_t)(b*SS + r0 + w*16 + l4) * (NHEADS*HDIM) + h*HDIM + g*8;
    #pragma unroll
    for (int st = 0; st < 2; ++st) {
      float4 t0 = *(const float4*)(qp + st*32);
      float4 t1 = *(const float4*)(qp + st*32 + 4);
      float f[8] = {t0.x*0.125f, t0.y*0.125f, t0.z*0.125f, t0.w*0.125f,
                    t1.x*0.125f, t1.y*0.125f, t1.z*0.125f, t1.w*0.125f};
      #pragma unroll
      for (int j = 0; j < 8; ++j) {
        bf16_t hi = (bf16_t)f[j];
        qh[st][j] = hi;
        ql[st][j] = (bf16_t)(f[j] - (float)hi);
      }
    }
  }
  const f32x4 fz = {0.f,0.f,0.f,0.f};
  f32x4 o[4]; o[0]=fz; o[1]=fz; o[2]=fz; o[3]=fz;
  float mrow[4] = {-3e38f,-3e38f,-3e38f,-3e38f};
  float lrow[4] = {0.f,0.f,0.f,0.f};

  int vkey = tid & 63;
  int dvb = (tid >> 6) * 16;
  int nch = qb + 1;
  for (int ch = 0; ch < nch; ++ch) {
    int kc = ch * 64;
    __syncthreads();
    #pragma unroll
    for (int it = 0; it < 4; ++it) {
      int slot = it*256 + tid;
      int key = slot >> 4, dq = (slot & 15) * 4;
      float4 kk4 = *(const float4*)(k + (size_t)(b*SS + kc + key)*(NKVH*HDIM) + kvh*HDIM + dq);
      bf16_t kh0 = (bf16_t)kk4.x, kh1 = (bf16_t)kk4.y, kh2 = (bf16_t)kk4.z, kh3 = (bf16_t)kk4.w;
      bf16x4 khv = {kh0, kh1, kh2, kh3};
      bf16x4 klv = { (bf16_t)(kk4.x-(float)kh0), (bf16_t)(kk4.y-(float)kh1),
                     (bf16_t)(kk4.z-(float)kh2), (bf16_t)(kk4.w-(float)kh3) };
      *(bf16x4*)&Khi[key][dq] = khv;
      *(bf16x4*)&Klo[key][dq] = klv;
      int dv = dvb + it*4;
      float4 vv4 = *(const float4*)(v + (size_t)(b*SS + kc + vkey)*(NKVH*HDIM) + kvh*HDIM + dv);
      float vf4[4] = {vv4.x, vv4.y, vv4.z, vv4.w};
      #pragma unroll
      for (int j = 0; j < 4; ++j) {
        bf16_t hi = (bf16_t)vf4[j];
        Vhi[dv+j][vkey] = hi;
        Vlo[dv+j][vkey] = (bf16_t)(vf4[j] - (float)hi);
      }
    }
    if (tid < 64) ms[tid] = (amask[b*SS + kc + tid] > 0) ? 0.f : -3e38f;
    __syncthreads();
    f32x4 s[4]; s[0]=fz; s[1]=fz; s[2]=fz; s[3]=fz;
    #pragma unroll
    for (int st = 0; st < 2; ++st) {
      #pragma unroll
      for (int c = 0; c < 4; ++c) {
        bf16x8 kfh = *(const bf16x8*)&Khi[c*16 + l4][st*32 + g*8];
        bf16x8 kfl = *(const bf16x8*)&Klo[c*16 + l4][st*32 + g*8];
        s[c] = __builtin_amdgcn_mfma_f32_16x16x32_bf16(qh[st], kfh, s[c], 0, 0, 0);
        s[c] = __builtin_amdgcn_mfma_f32_16x16x32_bf16(qh[st], kfl, s[c], 0, 0, 0);
        s[c] = __builtin_amdgcn_mfma_f32_16x16x32_bf16(ql[st], kfh, s[c], 0, 0, 0);
      }
    }
    #pragma unroll
    for (int c = 0; c < 4; ++c) {
      int kg = kc + c*16 + l4;
      float mk = ms[c*16 + l4];
      #pragma unroll
      for (int r = 0; r < 4; ++r) {
        int rowg = r0 + w*16 + g*4 + r;
        float sv = s[c][r] + mk;
        s[c][r] = (kg <= rowg) ? sv : -3e38f;
      }
    }
    float mnew[4], alpha[4];
    #pragma unroll
    for (int r = 0; r < 4; ++r) {
      float mc = fmaxf(fmaxf(s[0][r], s[1][r]), fmaxf(s[2][r], s[3][r]));
      mc = fmaxf(mc, __shfl_xor(mc, 1));
      mc = fmaxf(mc, __shfl_xor(mc, 2));
      mc = fmaxf(mc, __shfl_xor(mc, 4));
      mc = fmaxf(mc, __shfl_xor(mc, 8));
      mnew[r] = fmaxf(mrow[r], mc);
      alpha[r] = __expf(mrow[r] - mnew[r]);
      mrow[r] = mnew[r];
    }
    float rsum[4] = {0.f,0.f,0.f,0.f};
    #pragma unroll
    for (int c = 0; c < 4; ++c) {
      #pragma unroll
      for (int r = 0; r < 4; ++r) {
        float p = __expf(s[c][r] - mnew[r]);
        s[c][r] = p;
        rsum[r] += p;
      }
    }
    #pragma unroll
    for (int r = 0; r < 4; ++r) {
      float t = rsum[r];
      t += __shfl_xor(t, 1); t += __shfl_xor(t, 2);
      t += __shfl_xor(t, 4); t += __shfl_xor(t, 8);
      lrow[r] = lrow[r] * alpha[r] + t;
      o[0][r] *= alpha[r]; o[1][r] *= alpha[r]; o[2][r] *= alpha[r]; o[3][r] *= alpha[r];
    }
    #pragma unroll
    for (int c = 0; c < 4; ++c) {
      #pragma unroll
      for (int r = 0; r < 4; ++r) {
        float p = s[c][r];
        bf16_t hi = (bf16_t)p;
        Phi[w][g*4 + r][c*16 + l4] = hi;
        Plo[w][g*4 + r][c*16 + l4] = (bf16_t)(p - (float)hi);
      }
    }
    __syncthreads();
    #pragma unroll
    for (int st = 0; st < 2; ++st) {
      bf16x8 pfh = *(const bf16x8*)&Phi[w][l4][st*32 + g*8];
      bf16x8 pfl = *(const bf16x8*)&Plo[w][l4][st*32 + g*8];
      #pragma unroll
      for (int c = 0; c < 4; ++c) {
        bf16x8 vfh = *(const bf16x8*)&Vhi[c*16 + l4][st*32 + g*8];
        bf16x8 vfl = *(const bf16x8*)&Vlo[c*16 + l4][st*32 + g*8];
        o[c] = __builtin_amdgcn_mfma_f32_16x16x32_bf16(pfh, vfh, o[c], 0, 0, 0);
        o[c] = __builtin_amdgcn_mfma_f32_16x16x32_bf16(pfl, vfh, o[c], 0, 0, 0);
        o[c] = __builtin_amdgcn_mfma_f32_16x16x32_bf16(pfh, vfl, o[c], 0, 0, 0);
      }
    }
  }
  #pragma unroll
  for (int r = 0; r < 4; ++r) {
    float inv = (lrow[r] > 0.f) ? 1.f / lrow[r] : 0.f;
    int row = r0 + w*16 + g*4 + r;
    bf16_t* op = out + (size_t)(b*SS + row) * (NHEADS*HDIM) + h*HDIM;
    #pragma unroll
    for (int c = 0; c < 4; ++c)
      op[c*16 + l4] = (bf16_t)(o[c][r] * inv);
  }
}

// ---------------- router ----------------
__global__ __launch_bounds__(256) void router_kernel(
    const float* __restrict__ h2, const float* __restrict__ gw,
    float* __restrict__ logits_out, int* __restrict__ sel, float* __restrict__ wts,
    int* __restrict__ counts)
{
  int tid = threadIdx.x, lane = tid & 63, w = tid >> 6;
  int tok = blockIdx.x * 4 + w;
  float acc[NEXP] = {0.f,0.f,0.f,0.f,0.f,0.f,0.f,0.f};
  const float* xr = h2 + (size_t)tok * HH;
  for (int hh = lane; hh < HH; hh += 64) {
    float xv = xr[hh];
    const float* gr = gw + (size_t)hh * NEXP;
    #pragma unroll
    for (int e = 0; e < NEXP; ++e) acc[e] += xv * gr[e];
  }
  #pragma unroll
  for (int e = 0; e < NEXP; ++e) {
    #pragma unroll
    for (int off = 32; off > 0; off >>= 1) acc[e] += __shfl_xor(acc[e], off);
  }
  if (lane == 0) {
    float* lo = logits_out + (size_t)tok * NEXP;
    #pragma unroll
    for (int e = 0; e < NEXP; ++e) lo[e] = acc[e];
    int b0 = 0; float v0 = acc[0];
    #pragma unroll
    for (int e = 1; e < NEXP; ++e) if (acc[e] > v0) { v0 = acc[e]; b0 = e; }
    int b1 = -1; float v1 = -1e38f;
    #pragma unroll
    for (int e = 0; e < NEXP; ++e) if (e != b0 && acc[e] > v1) { v1 = acc[e]; b1 = e; }
    float wa = 1.f / (1.f + __expf(v1 - v0));
    sel[tok*2] = b0; sel[tok*2+1] = b1;
    wts[tok*2] = wa; wts[tok*2+1] = 1.f - wa;
    atomicAdd(&counts[b0], 1);
    atomicAdd(&counts[b1], 1);
  }
}

__global__ void scan_kernel(const int* __restrict__ counts, int* __restrict__ offsets,
                            int* __restrict__ fill)
{
  if (threadIdx.x == 0 && blockIdx.x == 0) {
    int o = 0;
    for (int e = 0; e < NEXP; ++e) { offsets[e] = o; o += counts[e]; fill[e] = 0; }
  }
}

__global__ __launch_bounds__(256) void scatter_kernel(
    const int* __restrict__ sel, const int* __restrict__ offsets, int* __restrict__ fill,
    int* __restrict__ etok, int* __restrict__ tslot)
{
  int t = blockIdx.x * 256 + threadIdx.x;
  if (t >= NTOK) return;
  #pragma unroll
  for (int s = 0; s < 2; ++s) {
    int e = sel[t*2 + s];
    int p = atomicAdd(&fill[e], 1);
    int slot = offsets[e] + p;
    etok[slot] = t;
    tslot[t*2 + s] = slot;
  }
}

// ---------------- MoE mm1: G[slot][IDIM] = hb(gather) @ w1t[e], bf16 out ----------------
__global__ __launch_bounds__(256) void moe_mm1(
    const bf16_t* __restrict__ hb, const bf16_t* __restrict__ w1t,
    const int* __restrict__ counts, const int* __restrict__ offsets,
    const int* __restrict__ etok, bf16_t* __restrict__ G)
{
  int e = blockIdx.z, cnt = counts[e], mb = blockIdx.y;
  if (mb * 128 >= cnt) return;
  int off = offsets[e];
  __shared__ __align__(16) bf16_t As[4096];
  __shared__ __align__(16) bf16_t Bs[4096];
  int tid = threadIdx.x, lane = tid & 63, w = tid >> 6;
  int l4 = lane & 15, g = lane >> 4;
  int n0 = blockIdx.x * 128;
  int lrow = w*16 + (lane >> 2), lk = (lane & 3) * 8;
  int r0 = mb*128 + lrow, r1 = r0 + 64;
  int t0 = etok[off + (r0 < cnt ? r0 : cnt-1)];
  int t1 = etok[off + (r1 < cnt ? r1 : cnt-1)];
  const bf16_t* ag0 = hb + (size_t)t0 * HH + lk;
  const bf16_t* ag1 = hb + (size_t)t1 * HH + lk;
  const bf16_t* Bt = w1t + (size_t)e * IDIM * HH;
  const bf16_t* bg0 = Bt + (size_t)(n0 + lrow) * HH + lk;
  const bf16_t* bg1 = bg0 + (size_t)64 * HH;
  bf16_t* lA0 = As + w*512;  bf16_t* lA1 = As + 2048 + w*512;
  bf16_t* lB0 = Bs + w*512;  bf16_t* lB1 = Bs + 2048 + w*512;
  const f32x4 fz = {0.f,0.f,0.f,0.f};
  f32x4 acc[4][4];
  #pragma unroll
  for (int i = 0; i < 4; ++i) { acc[i][0]=fz; acc[i][1]=fz; acc[i][2]=fz; acc[i][3]=fz; }
  int wm = (w >> 1) * 64, wn = (w & 1) * 64;
  for (int k0 = 0; k0 < HH; k0 += 32) {
    __syncthreads();
    gl16(ag0, lA0); gl16(ag1, lA1); gl16(bg0, lB0); gl16(bg1, lB1);
    ag0 += 32; ag1 += 32; bg0 += 32; bg1 += 32;
    __syncthreads();
    bf16x8 af[4], bfr[4];
    #pragma unroll
    for (int mi = 0; mi < 4; ++mi) af[mi] = *(const bf16x8*)&As[(wm + mi*16 + l4)*32 + g*8];
    #pragma unroll
    for (int ni = 0; ni < 4; ++ni) bfr[ni] = *(const bf16x8*)&Bs[(wn + ni*16 + l4)*32 + g*8];
    #pragma unroll
    for (int mi = 0; mi < 4; ++mi)
      #pragma unroll
      for (int ni = 0; ni < 4; ++ni)
        acc[mi][ni] = __builtin_amdgcn_mfma_f32_16x16x32_bf16(af[mi], bfr[ni], acc[mi][ni], 0, 0, 0);
  }
  #pragma unroll
  for (int mi = 0; mi < 4; ++mi) {
    #pragma unroll
    for (int r = 0; r < 4; ++r) {
      int slot = mb*128 + wm + mi*16 + g*4 + r;
      if (slot < cnt) {
        size_t rb = (size_t)(off + slot) * IDIM;
        #pragma unroll
        for (int ni = 0; ni < 4; ++ni)
          G[rb + n0 + wn + ni*16 + l4] = (bf16_t)acc[mi][ni][r];
      }
    }
  }
}

// ---------------- MoE mm3: act = silu(G) * (hb(gather) @ w3t[e]), in-place over G ----------------
__global__ __launch_bounds__(256) void moe_mm3(
    const bf16_t* __restrict__ hb, const bf16_t* __restrict__ w3t,
    const int* __restrict__ counts, const int* __restrict__ offsets,
    const int* __restrict__ etok, bf16_t* __restrict__ G)
{
  int e = blockIdx.z, cnt = counts[e], mb = blockIdx.y;
  if (mb * 128 >= cnt) return;
  int off = offsets[e];
  __shared__ __align__(16) bf16_t As[4096];
  __shared__ __align__(16) bf16_t Bs[4096];
  int tid = threadIdx.x, lane = tid & 63, w = tid >> 6;
  int l4 = lane & 15, g = lane >> 4;
  int n0 = blockIdx.x * 128;
  int lrow = w*16 + (lane >> 2), lk = (lane & 3) * 8;
  int r0 = mb*128 + lrow, r1 = r0 + 64;
  int t0 = etok[off + (r0 < cnt ? r0 : cnt-1)];
  int t1 = etok[off + (r1 < cnt ? r1 : cnt-1)];
  const bf16_t* ag0 = hb + (size_t)t0 * HH + lk;
  const bf16_t* ag1 = hb + (size_t)t1 * HH + lk;
  const bf16_t* Bt = w3t + (size_t)e * IDIM * HH;
  const bf16_t* bg0 = Bt + (size_t)(n0 + lrow) * HH + lk;
  const bf16_t* bg1 = bg0 + (size_t)64 * HH;
  bf16_t* lA0 = As + w*512;  bf16_t* lA1 = As + 2048 + w*512;
  bf16_t* lB0 = Bs + w*512;  bf16_t* lB1 = Bs + 2048 + w*512;
  const f32x4 fz = {0.f,0.f,0.f,0.f};
  f32x4 acc[4][4];
  #pragma unroll
  for (int i = 0; i < 4; ++i) { acc[i][0]=fz; acc[i][1]=fz; acc[i][2]=fz; acc[i][3]=fz; }
  int wm = (w >> 1) * 64, wn = (w & 1) * 64;
  for (int k0 = 0; k0 < HH; k0 += 32) {
    __syncthreads();
    gl16(ag0, lA0); gl16(ag1, lA1); gl16(bg0, lB0); gl16(bg1, lB1);
    ag0 += 32; ag1 += 32; bg0 += 32; bg1 += 32;
    __syncthreads();
    bf16x8 af[4], bfr[4];
    #pragma unroll
    for (int mi = 0; mi < 4; ++mi) af[mi] = *(const bf16x8*)&As[(wm + mi*16 + l4)*32 + g*8];
    #pragma unroll
    for (int ni = 0; ni < 4; ++ni) bfr[ni] = *(const bf16x8*)&Bs[(wn + ni*16 + l4)*32 + g*8];
    #pragma unroll
    for (int mi = 0; mi < 4; ++mi)
      #pragma unroll
      for (int ni = 0; ni < 4; ++ni)
        acc[mi][ni] = __builtin_amdgcn_mfma_f32_16x16x32_bf16(af[mi], bfr[ni], acc[mi][ni], 0, 0, 0);
  }
  #pragma unroll
  for (int mi = 0; mi < 4; ++mi) {
    #pragma unroll
    for (int r = 0; r < 4; ++r) {
      int slot = mb*128 + wm + mi*16 + g*4 + r;
      if (slot < cnt) {
        size_t rb = (size_t)(off + slot) * IDIM;
        #pragma unroll
        for (int ni = 0; ni < 4; ++ni) {
          size_t idx = rb + n0 + wn + ni*16 + l4;
          float gv = (float)G[idx];
          float sv = gv / (1.f + __expf(-gv));
          G[idx] = (bf16_t)(sv * acc[mi][ni][r]);
        }
      }
    }
  }
}

// ---------------- MoE mm2: eo[slot][HH] fp32 = act[slot] @ w2t[e] ----------------
__global__ __launch_bounds__(256) void moe_mm2(
    const bf16_t* __restrict__ act, const bf16_t* __restrict__ w2t,
    const int* __restrict__ counts, const int* __restrict__ offsets,
    float* __restrict__ eo)
{
  int e = blockIdx.z, cnt = counts[e], mb = blockIdx.y;
  if (mb * 128 >= cnt) return;
  int off = offsets[e];
  __shared__ __align__(16) bf16_t As[4096];
  __shared__ __align__(16) bf16_t Bs[4096];
  int tid = threadIdx.x, lane = tid & 63, w = tid >> 6;
  int l4 = lane & 15, g = lane >> 4;
  int n0 = blockIdx.x * 128;
  int lrow = w*16 + (lane >> 2), lk = (lane & 3) * 8;
  int r0 = mb*128 + lrow, r1 = r0 + 64;
  int cr0 = (r0 < cnt ? r0 : cnt-1), cr1 = (r1 < cnt ? r1 : cnt-1);
  const bf16_t* ag0 = act + (size_t)(off + cr0) * IDIM + lk;
  const bf16_t* ag1 = act + (size_t)(off + cr1) * IDIM + lk;
  const bf16_t* Bt = w2t + (size_t)e * HH * IDIM;
  const bf16_t* bg0 = Bt + (size_t)(n0 + lrow) * IDIM + lk;
  const bf16_t* bg1 = bg0 + (size_t)64 * IDIM;
  bf16_t* lA0 = As + w*512;  bf16_t* lA1 = As + 2048 + w*512;
  bf16_t* lB0 = Bs + w*512;  bf16_t* lB1 = Bs + 2048 + w*512;
  const f32x4 fz = {0.f,0.f,0.f,0.f};
  f32x4 acc[4][4];
  #pragma unroll
  for (int i = 0; i < 4; ++i) { acc[i][0]=fz; acc[i][1]=fz; acc[i][2]=fz; acc[i][3]=fz; }
  int wm = (w >> 1) * 64, wn = (w & 1) * 64;
  for (int k0 = 0; k0 < IDIM; k0 += 32) {
    __syncthreads();
    gl16(ag0, lA0); gl16(ag1, lA1); gl16(bg0, lB0); gl16(bg1, lB1);
    ag0 += 32; ag1 += 32; bg0 += 32; bg1 += 32;
    __syncthreads();
    bf16x8 af[4], bfr[4];
    #pragma unroll
    for (int mi = 0; mi < 4; ++mi) af[mi] = *(const bf16x8*)&As[(wm + mi*16 + l4)*32 + g*8];
    #pragma unroll
    for (int ni = 0; ni < 4; ++ni) bfr[ni] = *(const bf16x8*)&Bs[(wn + ni*16 + l4)*32 + g*8];
    #pragma unroll
    for (int mi = 0; mi < 4; ++mi)
      #pragma unroll
      for (int ni = 0; ni < 4; ++ni)
        acc[mi][ni] = __builtin_amdgcn_mfma_f32_16x16x32_bf16(af[mi], bfr[ni], acc[mi][ni], 0, 0, 0);
  }
  #pragma unroll
  for (int mi = 0; mi < 4; ++mi) {
    #pragma unroll
    for (int r = 0; r < 4; ++r) {
      int slot = mb*128 + wm + mi*16 + g*4 + r;
      if (slot < cnt) {
        size_t rb = (size_t)(off + slot) * HH;
        #pragma unroll
        for (int ni = 0; ni < 4; ++ni)
          eo[rb + n0 + wn + ni*16 + l4] = acc[mi][ni][r];
      }
    }
  }
}

// ---------------- combine: out[tok] += w0*eo[slot0] + w1*eo[slot1] ----------------
__global__ __launch_bounds__(256) void combine_kernel(
    const float* __restrict__ eo, const int* __restrict__ tslot,
    const float* __restrict__ wts, float* __restrict__ out)
{
  int t = blockIdx.x;
  int c = threadIdx.x * 4;
  int s0 = tslot[t*2], s1 = tslot[t*2 + 1];
  float w0 = wts[t*2], w1 = wts[t*2 + 1];
  float4 o = *(float4*)(out + (size_t)t * HH + c);
  float4 a = *(const float4*)(eo + (size_t)s0 * HH + c);
  float4 b = *(const float4*)(eo + (size_t)s1 * HH + c);
  o.x += w0*a.x + w1*b.x;
  o.y += w0*a.y + w1*b.y;
  o.z += w0*a.z + w1*b.z;
  o.w += w0*a.w + w1*b.w;
  *(float4*)(out + (size_t)t * HH + c) = o;
}

extern "C" void kernel_launch(void* const* d_in, const int* in_sizes, int n_in,
                              void* d_out, int out_size, void* d_ws, size_t ws_size,
                              hipStream_t stream)
{
  const float* x    = (const float*)d_in[0];
  const int*   am   = (const int*)d_in[1];
  const int*   pid  = (const int*)d_in[2];
  const float* n1w  = (const float*)d_in[3];
  const float* n2w  = (const float*)d_in[4];
  const float* wq   = (const float*)d_in[5];
  const float* wk   = (const float*)d_in[6];
  const float* wv   = (const float*)d_in[7];
  const float* wo   = (const float*)d_in[8];
  const float* gw   = (const float*)d_in[9];
  const float* w1   = (const float*)d_in[10];
  const float* w3   = (const float*)d_in[11];
  const float* w2   = (const float*)d_in[12];
  float* out = (float*)d_out;
  float* rlogits = out + (size_t)NTOK * HH;

  char* base = (char*)d_ws;
  bf16_t* hb  = (bf16_t*)(base);                        // 8 MB
  float*  h2  = (float*)(base + (8ull<<20));            // 16 MB
  float*  qb  = (float*)(base + (24ull<<20));           // 16 MB
  float*  kb  = (float*)(base + (40ull<<20));           // 4 MB
  float*  vb  = (float*)(base + (44ull<<20));           // 4 MB
  bf16_t* ob  = (bf16_t*)(base + (48ull<<20));          // 8 MB
  bf16_t* G   = (bf16_t*)(base + (24ull<<20));          // 32 MB, aliases qb/kb/vb/ob (dead)
  float*  eo  = (float*)(base + (56ull<<20));           // 32 MB
  bf16_t* wqt = (bf16_t*)(base + (88ull<<20));          // 2 MB
  bf16_t* wkt = (bf16_t*)(base + (90ull<<20));          // 0.5 MB
  bf16_t* wvt = (bf16_t*)(base + (90ull<<20) + (512ull<<10)); // 0.5 MB
  bf16_t* wot = (bf16_t*)(base + (91ull<<20));          // 2 MB
  bf16_t* w1t = (bf16_t*)(base + (93ull<<20));          // 32 MB
  bf16_t* w3t = (bf16_t*)(base + (125ull<<20));         // 32 MB
  bf16_t* w2t = (bf16_t*)(base + (157ull<<20));         // 32 MB
  char* sm = base + (189ull<<20);
  int*   sel   = (int*)sm;
  float* wts   = (float*)(sm + (64<<10));
  int*   etok  = (int*)(sm + (128<<10));
  int*   tslot = (int*)(sm + (192<<10));
  int* counts  = (int*)(sm + (256<<10));
  int* offsets = counts + 8;
  int* fill    = counts + 16;

  // ---- weight prep (bf16 transposed) ----
  transpose_cvt<<<dim3(16,16,1), 256, 0, stream>>>(wq, wqt, 1024, 1024);
  transpose_cvt<<<dim3(4,16,1),  256, 0, stream>>>(wk, wkt, 1024, 256);
  transpose_cvt<<<dim3(4,16,1),  256, 0, stream>>>(wv, wvt, 1024, 256);
  transpose_cvt<<<dim3(16,16,1), 256, 0, stream>>>(wo, wot, 1024, 1024);
  transpose_cvt<<<dim3(32,16,8), 256, 0, stream>>>(w1, w1t, 1024, 2048);
  transpose_cvt<<<dim3(32,16,8), 256, 0, stream>>>(w3, w3t, 1024, 2048);
  transpose_cvt<<<dim3(16,32,8), 256, 0, stream>>>(w2, w2t, 2048, 1024);
  hipMemsetAsync(counts, 0, 3 * 8 * sizeof(int), stream);

  // ---- attention block ----
  rmsnorm_kernel<<<NTOK, 256, 0, stream>>>(x, n1w, nullptr, hb);
  gemm_bt<<<dim3(8,32),  256, 0, stream>>>(hb, wqt, nullptr, qb, NHEADS*HDIM, HH);
  gemm_bt<<<dim3(2,32),  256, 0, stream>>>(hb, wkt, nullptr, kb, NKVH*HDIM, HH);
  gemm_bt<<<dim3(2,32),  256, 0, stream>>>(hb, wvt, nullptr, vb, NKVH*HDIM, HH);
  rope_kernel<<<(NTOK*640)/256, 256, 0, stream>>>(qb, kb, pid);
  attn_mfma_kernel<<<dim3(SS/64, BB*NHEADS), 256, 0, stream>>>(qb, kb, vb, am, ob);
  gemm_bt<<<dim3(8,32),  256, 0, stream>>>(ob, wot, x, out, HH, NHEADS*HDIM);

  // ---- MoE block ----
  rmsnorm_kernel<<<NTOK, 256, 0, stream>>>(out, n2w, h2, hb);
  router_kernel<<<NTOK/4, 256, 0, stream>>>(h2, gw, rlogits, sel, wts, counts);
  scan_kernel<<<1, 64, 0, stream>>>(counts, offsets, fill);
  scatter_kernel<<<NTOK/256, 256, 0, stream>>>(sel, offsets, fill, etok, tslot);
  moe_mm1<<<dim3(16,32,8), 256, 0, stream>>>(hb, w1t, counts, offsets, etok, G);
  moe_mm3<<<dim3(16,32,8), 256, 0, stream>>>(hb, w3t, counts, offsets, etok, G);
  moe_mm2<<<dim3(8,32,8),  256, 0, stream>>>(G, w2t, counts, offsets, eo);
  combine_kernel<<<NTOK, 256, 0, stream>>>(eo, tslot, wts, out);
}

// Round 5
// 981.744 us; speedup vs baseline: 2.4431x; 1.0447x over previous
//
#include <hip/hip_runtime.h>
#include <cstdint>
#include <cstddef>

#define BB 2
#define SS 2048
#define HH 1024
#define NHEADS 16
#define NKVH 4
#define HDIM 64
#define NEXP 8
#define IDIM 2048
#define NTOK (BB*SS)

typedef __bf16 bf16_t;
typedef bf16_t bf16x8 __attribute__((ext_vector_type(8)));
typedef bf16_t bf16x4 __attribute__((ext_vector_type(4)));
typedef float f32x4 __attribute__((ext_vector_type(4)));

// async global->LDS, 16B per lane; LDS dest = wave-uniform base + lane*16
static __device__ __forceinline__ void gl16(const void* g, void* l) {
  __builtin_amdgcn_global_load_lds(
      (const __attribute__((address_space(1))) unsigned int*)g,
      (__attribute__((address_space(3))) unsigned int*)l, 16, 0, 0);
}

// ---------------- weight transpose+convert: W fp32 [K][N] -> WT bf16 [N][K] ----------------
__global__ __launch_bounds__(256) void transpose_cvt(
    const float* __restrict__ W, bf16_t* __restrict__ WT, int K, int N)
{
  const float* Wm = W + (size_t)blockIdx.z * K * N;
  bf16_t* Tm = WT + (size_t)blockIdx.z * K * N;
  __shared__ float Ls[64][65];
  int tid = threadIdx.x;
  int k0 = blockIdx.y * 64, n0 = blockIdx.x * 64;
  int rr = tid >> 4, cc = (tid & 15) * 4;
  #pragma unroll
  for (int rep = 0; rep < 4; ++rep) {
    float4 vv = *(const float4*)(Wm + (size_t)(k0 + rep*16 + rr) * N + n0 + cc);
    Ls[rep*16 + rr][cc+0] = vv.x;
    Ls[rep*16 + rr][cc+1] = vv.y;
    Ls[rep*16 + rr][cc+2] = vv.z;
    Ls[rep*16 + rr][cc+3] = vv.w;
  }
  __syncthreads();
  int nn = tid >> 2, ks = (tid & 3) * 16;
  bf16x8 o0, o1;
  #pragma unroll
  for (int j = 0; j < 8; ++j) o0[j] = (bf16_t)Ls[ks + j][nn];
  #pragma unroll
  for (int j = 0; j < 8; ++j) o1[j] = (bf16_t)Ls[ks + 8 + j][nn];
  bf16_t* op = Tm + (size_t)(n0 + nn) * K + k0 + ks;
  *(bf16x8*)op = o0;
  *(bf16x8*)(op + 8) = o1;
}

// ---------------- RMSNorm: fp32 in, optional fp32 out + bf16 out ----------------
__global__ __launch_bounds__(256) void rmsnorm_kernel(
    const float* __restrict__ x, const float* __restrict__ w,
    float* __restrict__ outf, bf16_t* __restrict__ outb)
{
  int t = blockIdx.x;
  int tid = threadIdx.x;
  float4 v = ((const float4*)(x + (size_t)t * HH))[tid];
  float ss = v.x*v.x + v.y*v.y + v.z*v.z + v.w*v.w;
  #pragma unroll
  for (int off = 32; off > 0; off >>= 1) ss += __shfl_xor(ss, off);
  __shared__ float red[4];
  if ((tid & 63) == 0) red[tid >> 6] = ss;
  __syncthreads();
  float tot = red[0] + red[1] + red[2] + red[3];
  float scale = 1.0f / sqrtf(tot / (float)HH + 1e-6f);
  float4 wv = ((const float4*)w)[tid];
  float4 o;
  o.x = v.x * scale * wv.x;
  o.y = v.y * scale * wv.y;
  o.z = v.z * scale * wv.z;
  o.w = v.w * scale * wv.w;
  if (outf) ((float4*)(outf + (size_t)t * HH))[tid] = o;
  bf16x4 ob4 = { (bf16_t)o.x, (bf16_t)o.y, (bf16_t)o.z, (bf16_t)o.w };
  *(bf16x4*)(outb + (size_t)t * HH + tid*4) = ob4;
}

// ---------------- m97-style GEMM: C[M,N] fp32 = A_bf16[M,K] @ Bt_bf16[N,K] (+R) ----------------
__global__ __launch_bounds__(256) void gemm_bt(
    const bf16_t* __restrict__ A, const bf16_t* __restrict__ Bt,
    const float* __restrict__ R, float* __restrict__ C, int N, int K)
{
  __shared__ __align__(16) bf16_t As[4096];   // [128][32]
  __shared__ __align__(16) bf16_t Bs[4096];
  int tid = threadIdx.x, lane = tid & 63, w = tid >> 6;
  int l4 = lane & 15, g = lane >> 4;
  int m0 = blockIdx.y * 128, n0 = blockIdx.x * 128;
  int lrow = w*16 + (lane >> 2), lk = (lane & 3) * 8;
  const bf16_t* ag0 = A + (size_t)(m0 + lrow) * K + lk;
  const bf16_t* ag1 = ag0 + (size_t)64 * K;
  const bf16_t* bg0 = Bt + (size_t)(n0 + lrow) * K + lk;
  const bf16_t* bg1 = bg0 + (size_t)64 * K;
  bf16_t* lA0 = As + w*512;  bf16_t* lA1 = As + 2048 + w*512;
  bf16_t* lB0 = Bs + w*512;  bf16_t* lB1 = Bs + 2048 + w*512;
  const f32x4 fz = {0.f,0.f,0.f,0.f};
  f32x4 acc[4][4];
  #pragma unroll
  for (int i = 0; i < 4; ++i) { acc[i][0]=fz; acc[i][1]=fz; acc[i][2]=fz; acc[i][3]=fz; }
  int wm = (w >> 1) * 64, wn = (w & 1) * 64;
  for (int k0 = 0; k0 < K; k0 += 32) {
    __syncthreads();
    gl16(ag0, lA0); gl16(ag1, lA1); gl16(bg0, lB0); gl16(bg1, lB1);
    ag0 += 32; ag1 += 32; bg0 += 32; bg1 += 32;
    __syncthreads();
    bf16x8 af[4], bfr[4];
    #pragma unroll
    for (int mi = 0; mi < 4; ++mi) af[mi] = *(const bf16x8*)&As[(wm + mi*16 + l4)*32 + g*8];
    #pragma unroll
    for (int ni = 0; ni < 4; ++ni) bfr[ni] = *(const bf16x8*)&Bs[(wn + ni*16 + l4)*32 + g*8];
    #pragma unroll
    for (int mi = 0; mi < 4; ++mi)
      #pragma unroll
      for (int ni = 0; ni < 4; ++ni)
        acc[mi][ni] = __builtin_amdgcn_mfma_f32_16x16x32_bf16(af[mi], bfr[ni], acc[mi][ni], 0, 0, 0);
  }
  #pragma unroll
  for (int mi = 0; mi < 4; ++mi) {
    int rowb = m0 + wm + mi*16 + g*4;
    #pragma unroll
    for (int r = 0; r < 4; ++r) {
      size_t rb = (size_t)(rowb + r) * N;
      #pragma unroll
      for (int ni = 0; ni < 4; ++ni) {
        int col = n0 + wn + ni*16 + l4;
        float vv = acc[mi][ni][r];
        C[rb + col] = R ? vv + R[rb + col] : vv;
      }
    }
  }
}

// ---------------- RoPE (in-place on q and k) ----------------
__global__ __launch_bounds__(256) void rope_kernel(
    float* __restrict__ q, float* __restrict__ k, const int* __restrict__ pos_ids)
{
  int idx = blockIdx.x * 256 + threadIdx.x;
  int token = idx / 640;
  int rem = idx - token * 640;
  int head = rem >> 5;
  int i = rem & 31;
  float pos = (float)pos_ids[token];
  float inv = __expf(-(float)i * (9.210340371976184f / 32.0f));
  float ang = pos * inv;
  float s, c;
  sincosf(ang, &s, &c);
  float* p;
  if (head < NHEADS) p = q + (size_t)token * (NHEADS*HDIM) + head * HDIM;
  else               p = k + (size_t)token * (NKVH*HDIM) + (head - NHEADS) * HDIM;
  float x1 = p[i], x2 = p[i + 32];
  p[i]      = x1 * c - x2 * s;
  p[i + 32] = x2 * c + x1 * s;
}

// ---------------- pack K/V: fp32 -> swizzled bf16 hi/lo planes ----------------
// Khig/Klog: [bk][s][64] rows, seg' = seg ^ (s&7).
// Vhig/Vlog: [bk][chunk][d][64keys] rows, seg' = seg ^ (d&7).
__global__ __launch_bounds__(256) void pack_kv(
    const float* __restrict__ kb, const float* __restrict__ vb,
    bf16_t* __restrict__ Khig, bf16_t* __restrict__ Klog,
    bf16_t* __restrict__ Vhig, bf16_t* __restrict__ Vlog)
{
  __shared__ float Ls[64][68];
  int ch = blockIdx.x, bk = blockIdx.y;
  int b = bk >> 2, kvh = bk & 3;
  int tid = threadIdx.x;
  int key = tid >> 2, d0 = (tid & 3) * 16;
  size_t src = ((size_t)(b*SS + ch*64 + key) * NKVH + kvh) * HDIM + d0;
  float f[16];
  *(float4*)(f)     = *(const float4*)(kb + src);
  *(float4*)(f+4)   = *(const float4*)(kb + src + 4);
  *(float4*)(f+8)   = *(const float4*)(kb + src + 8);
  *(float4*)(f+12)  = *(const float4*)(kb + src + 12);
  size_t krow = ((size_t)bk*SS + ch*64 + key) * 64;
  int sw = key & 7, j0 = d0 >> 3;
  bf16x8 hi0, lo0, hi1, lo1;
  #pragma unroll
  for (int j = 0; j < 8; ++j) {
    bf16_t h = (bf16_t)f[j];     hi0[j] = h; lo0[j] = (bf16_t)(f[j]   - (float)h);
    bf16_t h2 = (bf16_t)f[8+j];  hi1[j] = h2; lo1[j] = (bf16_t)(f[8+j] - (float)h2);
  }
  *(bf16x8*)&Khig[krow + ((j0 ^ sw) << 3)]       = hi0;
  *(bf16x8*)&Khig[krow + (((j0+1) ^ sw) << 3)]   = hi1;
  *(bf16x8*)&Klog[krow + ((j0 ^ sw) << 3)]       = lo0;
  *(bf16x8*)&Klog[krow + (((j0+1) ^ sw) << 3)]   = lo1;
  // V transpose through LDS
  *(float4*)&Ls[key][d0]      = *(const float4*)(vb + src);
  *(float4*)&Ls[key][d0 + 4]  = *(const float4*)(vb + src + 4);
  *(float4*)&Ls[key][d0 + 8]  = *(const float4*)(vb + src + 8);
  *(float4*)&Ls[key][d0 + 12] = *(const float4*)(vb + src + 12);
  __syncthreads();
  int d = tid >> 2, k0 = (tid & 3) * 16;
  size_t vrow = ((size_t)(bk*32 + ch) * 64 + d) * 64;
  int swv = d & 7;
  #pragma unroll
  for (int half = 0; half < 2; ++half) {
    bf16x8 vh, vl;
    #pragma unroll
    for (int j = 0; j < 8; ++j) {
      float x = Ls[k0 + half*8 + j][d];
      bf16_t h = (bf16_t)x;
      vh[j] = h; vl[j] = (bf16_t)(x - (float)h);
    }
    int jj = (k0 >> 3) + half;
    *(bf16x8*)&Vhig[vrow + ((jj ^ swv) << 3)] = vh;
    *(bf16x8*)&Vlog[vrow + ((jj ^ swv) << 3)] = vl;
  }
}

// ---------------- causal GQA flash attention: packed K/V, gl16 staging, 128 q-rows ----------------
__global__ __launch_bounds__(256, 3) void attn_mfma_kernel(
    const float* __restrict__ q,
    const bf16_t* __restrict__ Khig, const bf16_t* __restrict__ Klog,
    const bf16_t* __restrict__ Vhig, const bf16_t* __restrict__ Vlog,
    const int* __restrict__ amask, bf16_t* __restrict__ out)
{
  __shared__ __align__(16) bf16_t Khi[4096], Klo[4096], Vhi[4096], Vlo[4096];
  __shared__ bf16_t Phi[4][16][72], Plo[4][16][72];
  __shared__ float ms[64];
  int tid = threadIdx.x, lane = tid & 63, w = tid >> 6;
  int l4 = lane & 15, g = lane >> 4;
  int bh = blockIdx.y;
  int b = bh >> 4, h = bh & 15, kvh = h >> 2;
  int bk = b * NKVH + kvh;
  int qb = gridDim.x - 1 - blockIdx.x;   // heavy blocks first
  int r0 = qb * 128;

  bf16x8 qh[2][2], ql[2][2];
  #pragma unroll
  for (int mi = 0; mi < 2; ++mi) {
    const float* qp = q + (size_t)(b*SS + r0 + mi*64 + w*16 + l4) * (NHEADS*HDIM) + h*HDIM + g*8;
    #pragma unroll
    for (int st = 0; st < 2; ++st) {
      float4 t0 = *(const float4*)(qp + st*32);
      float4 t1 = *(const float4*)(qp + st*32 + 4);
      float f[8] = {t0.x*0.125f, t0.y*0.125f, t0.z*0.125f, t0.w*0.125f,
                    t1.x*0.125f, t1.y*0.125f, t1.z*0.125f, t1.w*0.125f};
      #pragma unroll
      for (int j = 0; j < 8; ++j) {
        bf16_t hi = (bf16_t)f[j];
        qh[mi][st][j] = hi;
        ql[mi][st][j] = (bf16_t)(f[j] - (float)hi);
      }
    }
  }
  const f32x4 fz = {0.f,0.f,0.f,0.f};
  f32x4 o[2][4];
  float mrow[2][4], lrow[2][4];
  #pragma unroll
  for (int mi = 0; mi < 2; ++mi)
    #pragma unroll
    for (int c = 0; c < 4; ++c) { o[mi][c] = fz; mrow[mi][c] = -3e38f; lrow[mi][c] = 0.f; }

  const bf16_t* Khb = Khig + (size_t)bk*SS*64;
  const bf16_t* Klb = Klog + (size_t)bk*SS*64;
  const bf16_t* Vhb = Vhig + (size_t)bk*SS*64;
  const bf16_t* Vlb = Vlog + (size_t)bk*SS*64;
  int nch = 2*qb + 2;
  for (int ch = 0; ch < nch; ++ch) {
    int kc = ch * 64;
    __syncthreads();
    {
      size_t ko = (size_t)(kc + w*16) * 64 + lane*8;
      gl16(Khb + ko,       Khi + w*1024);
      gl16(Khb + ko + 512, Khi + w*1024 + 512);
      gl16(Klb + ko,       Klo + w*1024);
      gl16(Klb + ko + 512, Klo + w*1024 + 512);
      size_t vo = (size_t)ch*4096 + (size_t)(w*16)*64 + lane*8;
      gl16(Vhb + vo,       Vhi + w*1024);
      gl16(Vhb + vo + 512, Vhi + w*1024 + 512);
      gl16(Vlb + vo,       Vlo + w*1024);
      gl16(Vlb + vo + 512, Vlo + w*1024 + 512);
    }
    if (tid < 64) ms[tid] = (amask[b*SS + kc + tid] > 0) ? 0.f : -3e38f;
    __syncthreads();
    #pragma unroll
    for (int mi = 0; mi < 2; ++mi) {
      int tbase = r0 + mi*64 + w*16;
      if (kc > tbase + 15) continue;     // wave-uniform skip: tile fully masked
      f32x4 s[4]; s[0]=fz; s[1]=fz; s[2]=fz; s[3]=fz;
      #pragma unroll
      for (int st = 0; st < 2; ++st) {
        #pragma unroll
        for (int c = 0; c < 4; ++c) {
          int po = (c*16 + l4)*64 + (((st*4 + g) ^ (l4 & 7)) << 3);
          bf16x8 kfh = *(const bf16x8*)&Khi[po];
          bf16x8 kfl = *(const bf16x8*)&Klo[po];
          s[c] = __builtin_amdgcn_mfma_f32_16x16x32_bf16(qh[mi][st], kfh, s[c], 0, 0, 0);
          s[c] = __builtin_amdgcn_mfma_f32_16x16x32_bf16(qh[mi][st], kfl, s[c], 0, 0, 0);
          s[c] = __builtin_amdgcn_mfma_f32_16x16x32_bf16(ql[mi][st], kfh, s[c], 0, 0, 0);
        }
      }
      #pragma unroll
      for (int c = 0; c < 4; ++c) {
        int kg = kc + c*16 + l4;
        float mk = ms[c*16 + l4];
        #pragma unroll
        for (int r = 0; r < 4; ++r) {
          int rowg = tbase + g*4 + r;
          float sv = s[c][r] + mk;
          s[c][r] = (kg <= rowg) ? sv : -3e38f;
        }
      }
      float mnew[4], alpha[4];
      #pragma unroll
      for (int r = 0; r < 4; ++r) {
        float mc = fmaxf(fmaxf(s[0][r], s[1][r]), fmaxf(s[2][r], s[3][r]));
        mc = fmaxf(mc, __shfl_xor(mc, 1));
        mc = fmaxf(mc, __shfl_xor(mc, 2));
        mc = fmaxf(mc, __shfl_xor(mc, 4));
        mc = fmaxf(mc, __shfl_xor(mc, 8));
        mnew[r] = fmaxf(mrow[mi][r], mc);
        alpha[r] = __expf(mrow[mi][r] - mnew[r]);
        mrow[mi][r] = mnew[r];
      }
      float rsum[4] = {0.f,0.f,0.f,0.f};
      #pragma unroll
      for (int c = 0; c < 4; ++c) {
        #pragma unroll
        for (int r = 0; r < 4; ++r) {
          float p = __expf(s[c][r] - mnew[r]);
          s[c][r] = p;
          rsum[r] += p;
        }
      }
      #pragma unroll
      for (int r = 0; r < 4; ++r) {
        float t = rsum[r];
        t += __shfl_xor(t, 1); t += __shfl_xor(t, 2);
        t += __shfl_xor(t, 4); t += __shfl_xor(t, 8);
        lrow[mi][r] = lrow[mi][r] * alpha[r] + t;
        o[mi][0][r] *= alpha[r]; o[mi][1][r] *= alpha[r];
        o[mi][2][r] *= alpha[r]; o[mi][3][r] *= alpha[r];
      }
      #pragma unroll
      for (int c = 0; c < 4; ++c) {
        #pragma unroll
        for (int r = 0; r < 4; ++r) {
          float p = s[c][r];
          bf16_t hi = (bf16_t)p;
          Phi[w][g*4 + r][c*16 + l4] = hi;
          Plo[w][g*4 + r][c*16 + l4] = (bf16_t)(p - (float)hi);
        }
      }
      // Ps is wave-private: no barrier needed
      #pragma unroll
      for (int st = 0; st < 2; ++st) {
        bf16x8 pfh = *(const bf16x8*)&Phi[w][l4][st*32 + g*8];
        bf16x8 pfl = *(const bf16x8*)&Plo[w][l4][st*32 + g*8];
        #pragma unroll
        for (int c = 0; c < 4; ++c) {
          int po = (c*16 + l4)*64 + (((st*4 + g) ^ (l4 & 7)) << 3);
          bf16x8 vfh = *(const bf16x8*)&Vhi[po];
          bf16x8 vfl = *(const bf16x8*)&Vlo[po];
          o[mi][c] = __builtin_amdgcn_mfma_f32_16x16x32_bf16(pfh, vfh, o[mi][c], 0, 0, 0);
          o[mi][c] = __builtin_amdgcn_mfma_f32_16x16x32_bf16(pfl, vfh, o[mi][c], 0, 0, 0);
          o[mi][c] = __builtin_amdgcn_mfma_f32_16x16x32_bf16(pfh, vfl, o[mi][c], 0, 0, 0);
        }
      }
    }
  }
  #pragma unroll
  for (int mi = 0; mi < 2; ++mi) {
    #pragma unroll
    for (int r = 0; r < 4; ++r) {
      float inv = (lrow[mi][r] > 0.f) ? 1.f / lrow[mi][r] : 0.f;
      int row = r0 + mi*64 + w*16 + g*4 + r;
      bf16_t* op = out + (size_t)(b*SS + row) * (NHEADS*HDIM) + h*HDIM;
      #pragma unroll
      for (int c = 0; c < 4; ++c)
        op[c*16 + l4] = (bf16_t)(o[mi][c][r] * inv);
    }
  }
}

// ---------------- router ----------------
__global__ __launch_bounds__(256) void router_kernel(
    const float* __restrict__ h2, const float* __restrict__ gw,
    float* __restrict__ logits_out, int* __restrict__ sel, float* __restrict__ wts,
    int* __restrict__ counts)
{
  int tid = threadIdx.x, lane = tid & 63, w = tid >> 6;
  int tok = blockIdx.x * 4 + w;
  float acc[NEXP] = {0.f,0.f,0.f,0.f,0.f,0.f,0.f,0.f};
  const float* xr = h2 + (size_t)tok * HH;
  for (int hh = lane; hh < HH; hh += 64) {
    float xv = xr[hh];
    const float* gr = gw + (size_t)hh * NEXP;
    #pragma unroll
    for (int e = 0; e < NEXP; ++e) acc[e] += xv * gr[e];
  }
  #pragma unroll
  for (int e = 0; e < NEXP; ++e) {
    #pragma unroll
    for (int off = 32; off > 0; off >>= 1) acc[e] += __shfl_xor(acc[e], off);
  }
  if (lane == 0) {
    float* lo = logits_out + (size_t)tok * NEXP;
    #pragma unroll
    for (int e = 0; e < NEXP; ++e) lo[e] = acc[e];
    int b0 = 0; float v0 = acc[0];
    #pragma unroll
    for (int e = 1; e < NEXP; ++e) if (acc[e] > v0) { v0 = acc[e]; b0 = e; }
    int b1 = -1; float v1 = -1e38f;
    #pragma unroll
    for (int e = 0; e < NEXP; ++e) if (e != b0 && acc[e] > v1) { v1 = acc[e]; b1 = e; }
    float wa = 1.f / (1.f + __expf(v1 - v0));
    sel[tok*2] = b0; sel[tok*2+1] = b1;
    wts[tok*2] = wa; wts[tok*2+1] = 1.f - wa;
    atomicAdd(&counts[b0], 1);
    atomicAdd(&counts[b1], 1);
  }
}

__global__ void scan_kernel(const int* __restrict__ counts, int* __restrict__ offsets,
                            int* __restrict__ fill)
{
  if (threadIdx.x == 0 && blockIdx.x == 0) {
    int o = 0;
    for (int e = 0; e < NEXP; ++e) { offsets[e] = o; o += counts[e]; fill[e] = 0; }
  }
}

__global__ __launch_bounds__(256) void scatter_kernel(
    const int* __restrict__ sel, const int* __restrict__ offsets, int* __restrict__ fill,
    int* __restrict__ etok, int* __restrict__ tslot)
{
  int t = blockIdx.x * 256 + threadIdx.x;
  if (t >= NTOK) return;
  #pragma unroll
  for (int s = 0; s < 2; ++s) {
    int e = sel[t*2 + s];
    int p = atomicAdd(&fill[e], 1);
    int slot = offsets[e] + p;
    etok[slot] = t;
    tslot[t*2 + s] = slot;
  }
}

// ---------------- MoE mm1: G[slot][IDIM] = hb(gather) @ w1t[e], bf16 out ----------------
__global__ __launch_bounds__(256) void moe_mm1(
    const bf16_t* __restrict__ hb, const bf16_t* __restrict__ w1t,
    const int* __restrict__ counts, const int* __restrict__ offsets,
    const int* __restrict__ etok, bf16_t* __restrict__ G)
{
  int e = blockIdx.z, cnt = counts[e], mb = blockIdx.y;
  if (mb * 128 >= cnt) return;
  int off = offsets[e];
  __shared__ __align__(16) bf16_t As[4096];
  __shared__ __align__(16) bf16_t Bs[4096];
  int tid = threadIdx.x, lane = tid & 63, w = tid >> 6;
  int l4 = lane & 15, g = lane >> 4;
  int n0 = blockIdx.x * 128;
  int lrow = w*16 + (lane >> 2), lk = (lane & 3) * 8;
  int r0 = mb*128 + lrow, r1 = r0 + 64;
  int t0 = etok[off + (r0 < cnt ? r0 : cnt-1)];
  int t1 = etok[off + (r1 < cnt ? r1 : cnt-1)];
  const bf16_t* ag0 = hb + (size_t)t0 * HH + lk;
  const bf16_t* ag1 = hb + (size_t)t1 * HH + lk;
  const bf16_t* Bt = w1t + (size_t)e * IDIM * HH;
  const bf16_t* bg0 = Bt + (size_t)(n0 + lrow) * HH + lk;
  const bf16_t* bg1 = bg0 + (size_t)64 * HH;
  bf16_t* lA0 = As + w*512;  bf16_t* lA1 = As + 2048 + w*512;
  bf16_t* lB0 = Bs + w*512;  bf16_t* lB1 = Bs + 2048 + w*512;
  const f32x4 fz = {0.f,0.f,0.f,0.f};
  f32x4 acc[4][4];
  #pragma unroll
  for (int i = 0; i < 4; ++i) { acc[i][0]=fz; acc[i][1]=fz; acc[i][2]=fz; acc[i][3]=fz; }
  int wm = (w >> 1) * 64, wn = (w & 1) * 64;
  for (int k0 = 0; k0 < HH; k0 += 32) {
    __syncthreads();
    gl16(ag0, lA0); gl16(ag1, lA1); gl16(bg0, lB0); gl16(bg1, lB1);
    ag0 += 32; ag1 += 32; bg0 += 32; bg1 += 32;
    __syncthreads();
    bf16x8 af[4], bfr[4];
    #pragma unroll
    for (int mi = 0; mi < 4; ++mi) af[mi] = *(const bf16x8*)&As[(wm + mi*16 + l4)*32 + g*8];
    #pragma unroll
    for (int ni = 0; ni < 4; ++ni) bfr[ni] = *(const bf16x8*)&Bs[(wn + ni*16 + l4)*32 + g*8];
    #pragma unroll
    for (int mi = 0; mi < 4; ++mi)
      #pragma unroll
      for (int ni = 0; ni < 4; ++ni)
        acc[mi][ni] = __builtin_amdgcn_mfma_f32_16x16x32_bf16(af[mi], bfr[ni], acc[mi][ni], 0, 0, 0);
  }
  #pragma unroll
  for (int mi = 0; mi < 4; ++mi) {
    #pragma unroll
    for (int r = 0; r < 4; ++r) {
      int slot = mb*128 + wm + mi*16 + g*4 + r;
      if (slot < cnt) {
        size_t rb = (size_t)(off + slot) * IDIM;
        #pragma unroll
        for (int ni = 0; ni < 4; ++ni)
          G[rb + n0 + wn + ni*16 + l4] = (bf16_t)acc[mi][ni][r];
      }
    }
  }
}

// ---------------- MoE mm3: act = silu(G) * (hb(gather) @ w3t[e]), in-place over G ----------------
__global__ __launch_bounds__(256) void moe_mm3(
    const bf16_t* __restrict__ hb, const bf16_t* __restrict__ w3t,
    const int* __restrict__ counts, const int* __restrict__ offsets,
    const int* __restrict__ etok, bf16_t* __restrict__ G)
{
  int e = blockIdx.z, cnt = counts[e], mb = blockIdx.y;
  if (mb * 128 >= cnt) return;
  int off = offsets[e];
  __shared__ __align__(16) bf16_t As[4096];
  __shared__ __align__(16) bf16_t Bs[4096];
  int tid = threadIdx.x, lane = tid & 63, w = tid >> 6;
  int l4 = lane & 15, g = lane >> 4;
  int n0 = blockIdx.x * 128;
  int lrow = w*16 + (lane >> 2), lk = (lane & 3) * 8;
  int r0 = mb*128 + lrow, r1 = r0 + 64;
  int t0 = etok[off + (r0 < cnt ? r0 : cnt-1)];
  int t1 = etok[off + (r1 < cnt ? r1 : cnt-1)];
  const bf16_t* ag0 = hb + (size_t)t0 * HH + lk;
  const bf16_t* ag1 = hb + (size_t)t1 * HH + lk;
  const bf16_t* Bt = w3t + (size_t)e * IDIM * HH;
  const bf16_t* bg0 = Bt + (size_t)(n0 + lrow) * HH + lk;
  const bf16_t* bg1 = bg0 + (size_t)64 * HH;
  bf16_t* lA0 = As + w*512;  bf16_t* lA1 = As + 2048 + w*512;
  bf16_t* lB0 = Bs + w*512;  bf16_t* lB1 = Bs + 2048 + w*512;
  const f32x4 fz = {0.f,0.f,0.f,0.f};
  f32x4 acc[4][4];
  #pragma unroll
  for (int i = 0; i < 4; ++i) { acc[i][0]=fz; acc[i][1]=fz; acc[i][2]=fz; acc[i][3]=fz; }
  int wm = (w >> 1) * 64, wn = (w & 1) * 64;
  for (int k0 = 0; k0 < HH; k0 += 32) {
    __syncthreads();
    gl16(ag0, lA0); gl16(ag1, lA1); gl16(bg0, lB0); gl16(bg1, lB1);
    ag0 += 32; ag1 += 32; bg0 += 32; bg1 += 32;
    __syncthreads();
    bf16x8 af[4], bfr[4];
    #pragma unroll
    for (int mi = 0; mi < 4; ++mi) af[mi] = *(const bf16x8*)&As[(wm + mi*16 + l4)*32 + g*8];
    #pragma unroll
    for (int ni = 0; ni < 4; ++ni) bfr[ni] = *(const bf16x8*)&Bs[(wn + ni*16 + l4)*32 + g*8];
    #pragma unroll
    for (int mi = 0; mi < 4; ++mi)
      #pragma unroll
      for (int ni = 0; ni < 4; ++ni)
        acc[mi][ni] = __builtin_amdgcn_mfma_f32_16x16x32_bf16(af[mi], bfr[ni], acc[mi][ni], 0, 0, 0);
  }
  #pragma unroll
  for (int mi = 0; mi < 4; ++mi) {
    #pragma unroll
    for (int r = 0; r < 4; ++r) {
      int slot = mb*128 + wm + mi*16 + g*4 + r;
      if (slot < cnt) {
        size_t rb = (size_t)(off + slot) * IDIM;
        #pragma unroll
        for (int ni = 0; ni < 4; ++ni) {
          size_t idx = rb + n0 + wn + ni*16 + l4;
          float gv = (float)G[idx];
          float sv = gv / (1.f + __expf(-gv));
          G[idx] = (bf16_t)(sv * acc[mi][ni][r]);
        }
      }
    }
  }
}

// ---------------- MoE mm2: eo[slot][HH] fp32 = act[slot] @ w2t[e] ----------------
__global__ __launch_bounds__(256) void moe_mm2(
    const bf16_t* __restrict__ act, const bf16_t* __restrict__ w2t,
    const int* __restrict__ counts, const int* __restrict__ offsets,
    float* __restrict__ eo)
{
  int e = blockIdx.z, cnt = counts[e], mb = blockIdx.y;
  if (mb * 128 >= cnt) return;
  int off = offsets[e];
  __shared__ __align__(16) bf16_t As[4096];
  __shared__ __align__(16) bf16_t Bs[4096];
  int tid = threadIdx.x, lane = tid & 63, w = tid >> 6;
  int l4 = lane & 15, g = lane >> 4;
  int n0 = blockIdx.x * 128;
  int lrow = w*16 + (lane >> 2), lk = (lane & 3) * 8;
  int r0 = mb*128 + lrow, r1 = r0 + 64;
  int cr0 = (r0 < cnt ? r0 : cnt-1), cr1 = (r1 < cnt ? r1 : cnt-1);
  const bf16_t* ag0 = act + (size_t)(off + cr0) * IDIM + lk;
  const bf16_t* ag1 = act + (size_t)(off + cr1) * IDIM + lk;
  const bf16_t* Bt = w2t + (size_t)e * HH * IDIM;
  const bf16_t* bg0 = Bt + (size_t)(n0 + lrow) * IDIM + lk;
  const bf16_t* bg1 = bg0 + (size_t)64 * IDIM;
  bf16_t* lA0 = As + w*512;  bf16_t* lA1 = As + 2048 + w*512;
  bf16_t* lB0 = Bs + w*512;  bf16_t* lB1 = Bs + 2048 + w*512;
  const f32x4 fz = {0.f,0.f,0.f,0.f};
  f32x4 acc[4][4];
  #pragma unroll
  for (int i = 0; i < 4; ++i) { acc[i][0]=fz; acc[i][1]=fz; acc[i][2]=fz; acc[i][3]=fz; }
  int wm = (w >> 1) * 64, wn = (w & 1) * 64;
  for (int k0 = 0; k0 < IDIM; k0 += 32) {
    __syncthreads();
    gl16(ag0, lA0); gl16(ag1, lA1); gl16(bg0, lB0); gl16(bg1, lB1);
    ag0 += 32; ag1 += 32; bg0 += 32; bg1 += 32;
    __syncthreads();
    bf16x8 af[4], bfr[4];
    #pragma unroll
    for (int mi = 0; mi < 4; ++mi) af[mi] = *(const bf16x8*)&As[(wm + mi*16 + l4)*32 + g*8];
    #pragma unroll
    for (int ni = 0; ni < 4; ++ni) bfr[ni] = *(const bf16x8*)&Bs[(wn + ni*16 + l4)*32 + g*8];
    #pragma unroll
    for (int mi = 0; mi < 4; ++mi)
      #pragma unroll
      for (int ni = 0; ni < 4; ++ni)
        acc[mi][ni] = __builtin_amdgcn_mfma_f32_16x16x32_bf16(af[mi], bfr[ni], acc[mi][ni], 0, 0, 0);
  }
  #pragma unroll
  for (int mi = 0; mi < 4; ++mi) {
    #pragma unroll
    for (int r = 0; r < 4; ++r) {
      int slot = mb*128 + wm + mi*16 + g*4 + r;
      if (slot < cnt) {
        size_t rb = (size_t)(off + slot) * HH;
        #pragma unroll
        for (int ni = 0; ni < 4; ++ni)
          eo[rb + n0 + wn + ni*16 + l4] = acc[mi][ni][r];
      }
    }
  }
}

// ---------------- combine: out[tok] += w0*eo[slot0] + w1*eo[slot1] ----------------
__global__ __launch_bounds__(256) void combine_kernel(
    const float* __restrict__ eo, const int* __restrict__ tslot,
    const float* __restrict__ wts, float* __restrict__ out)
{
  int t = blockIdx.x;
  int c = threadIdx.x * 4;
  int s0 = tslot[t*2], s1 = tslot[t*2 + 1];
  float w0 = wts[t*2], w1 = wts[t*2 + 1];
  float4 o = *(float4*)(out + (size_t)t * HH + c);
  float4 a = *(const float4*)(eo + (size_t)s0 * HH + c);
  float4 b = *(const float4*)(eo + (size_t)s1 * HH + c);
  o.x += w0*a.x + w1*b.x;
  o.y += w0*a.y + w1*b.y;
  o.z += w0*a.z + w1*b.z;
  o.w += w0*a.w + w1*b.w;
  *(float4*)(out + (size_t)t * HH + c) = o;
}

extern "C" void kernel_launch(void* const* d_in, const int* in_sizes, int n_in,
                              void* d_out, int out_size, void* d_ws, size_t ws_size,
                              hipStream_t stream)
{
  const float* x    = (const float*)d_in[0];
  const int*   am   = (const int*)d_in[1];
  const int*   pid  = (const int*)d_in[2];
  const float* n1w  = (const float*)d_in[3];
  const float* n2w  = (const float*)d_in[4];
  const float* wq   = (const float*)d_in[5];
  const float* wk   = (const float*)d_in[6];
  const float* wv   = (const float*)d_in[7];
  const float* wo   = (const float*)d_in[8];
  const float* gw   = (const float*)d_in[9];
  const float* w1   = (const float*)d_in[10];
  const float* w3   = (const float*)d_in[11];
  const float* w2   = (const float*)d_in[12];
  float* out = (float*)d_out;
  float* rlogits = out + (size_t)NTOK * HH;

  char* base = (char*)d_ws;
  bf16_t* hb  = (bf16_t*)(base);                        // 8 MB
  float*  h2  = (float*)(base + (8ull<<20));            // 16 MB
  float*  qb  = (float*)(base + (24ull<<20));           // 16 MB
  float*  kb  = (float*)(base + (40ull<<20));           // 4 MB
  float*  vb  = (float*)(base + (44ull<<20));           // 4 MB
  bf16_t* ob  = (bf16_t*)(base + (48ull<<20));          // 8 MB
  bf16_t* G   = (bf16_t*)(base + (24ull<<20));          // 32 MB, aliases qb/kb/vb (dead by MoE)
  float*  eo  = (float*)(base + (56ull<<20));           // 32 MB (MoE phase)
  bf16_t* Khig = (bf16_t*)(base + (56ull<<20));         // 2 MB  (attn phase; inside eo, dead by MoE)
  bf16_t* Klog = (bf16_t*)(base + (58ull<<20));         // 2 MB
  bf16_t* Vhig = (bf16_t*)(base + (60ull<<20));         // 2 MB
  bf16_t* Vlog = (bf16_t*)(base + (62ull<<20));         // 2 MB
  bf16_t* wqt = (bf16_t*)(base + (88ull<<20));          // 2 MB
  bf16_t* wkt = (bf16_t*)(base + (90ull<<20));          // 0.5 MB
  bf16_t* wvt = (bf16_t*)(base + (90ull<<20) + (512ull<<10)); // 0.5 MB
  bf16_t* wot = (bf16_t*)(base + (91ull<<20));          // 2 MB
  bf16_t* w1t = (bf16_t*)(base + (93ull<<20));          // 32 MB
  bf16_t* w3t = (bf16_t*)(base + (125ull<<20));         // 32 MB
  bf16_t* w2t = (bf16_t*)(base + (157ull<<20));         // 32 MB
  char* sm = base + (189ull<<20);
  int*   sel   = (int*)sm;
  float* wts   = (float*)(sm + (64<<10));
  int*   etok  = (int*)(sm + (128<<10));
  int*   tslot = (int*)(sm + (192<<10));
  int* counts  = (int*)(sm + (256<<10));
  int* offsets = counts + 8;
  int* fill    = counts + 16;

  // ---- weight prep (bf16 transposed) ----
  transpose_cvt<<<dim3(16,16,1), 256, 0, stream>>>(wq, wqt, 1024, 1024);
  transpose_cvt<<<dim3(4,16,1),  256, 0, stream>>>(wk, wkt, 1024, 256);
  transpose_cvt<<<dim3(4,16,1),  256, 0, stream>>>(wv, wvt, 1024, 256);
  transpose_cvt<<<dim3(16,16,1), 256, 0, stream>>>(wo, wot, 1024, 1024);
  transpose_cvt<<<dim3(32,16,8), 256, 0, stream>>>(w1, w1t, 1024, 2048);
  transpose_cvt<<<dim3(32,16,8), 256, 0, stream>>>(w3, w3t, 1024, 2048);
  transpose_cvt<<<dim3(16,32,8), 256, 0, stream>>>(w2, w2t, 2048, 1024);
  hipMemsetAsync(counts, 0, 3 * 8 * sizeof(int), stream);

  // ---- attention block ----
  rmsnorm_kernel<<<NTOK, 256, 0, stream>>>(x, n1w, nullptr, hb);
  gemm_bt<<<dim3(8,32),  256, 0, stream>>>(hb, wqt, nullptr, qb, NHEADS*HDIM, HH);
  gemm_bt<<<dim3(2,32),  256, 0, stream>>>(hb, wkt, nullptr, kb, NKVH*HDIM, HH);
  gemm_bt<<<dim3(2,32),  256, 0, stream>>>(hb, wvt, nullptr, vb, NKVH*HDIM, HH);
  rope_kernel<<<(NTOK*640)/256, 256, 0, stream>>>(qb, kb, pid);
  pack_kv<<<dim3(32, BB*NKVH), 256, 0, stream>>>(kb, vb, Khig, Klog, Vhig, Vlog);
  attn_mfma_kernel<<<dim3(SS/128, BB*NHEADS), 256, 0, stream>>>(qb, Khig, Klog, Vhig, Vlog, am, ob);
  gemm_bt<<<dim3(8,32),  256, 0, stream>>>(ob, wot, x, out, HH, NHEADS*HDIM);

  // ---- MoE block ----
  rmsnorm_kernel<<<NTOK, 256, 0, stream>>>(out, n2w, h2, hb);
  router_kernel<<<NTOK/4, 256, 0, stream>>>(h2, gw, rlogits, sel, wts, counts);
  scan_kernel<<<1, 64, 0, stream>>>(counts, offsets, fill);
  scatter_kernel<<<NTOK/256, 256, 0, stream>>>(sel, offsets, fill, etok, tslot);
  moe_mm1<<<dim3(16,32,8), 256, 0, stream>>>(hb, w1t, counts, offsets, etok, G);
  moe_mm3<<<dim3(16,32,8), 256, 0, stream>>>(hb, w3t, counts, offsets, etok, G);
  moe_mm2<<<dim3(8,32,8),  256, 0, stream>>>(G, w2t, counts, offsets, eo);
  combine_kernel<<<NTOK, 256, 0, stream>>>(eo, tslot, wts, out);
}